// Round 12
// baseline (438.085 us; speedup 1.0000x reference)
//
#include <hip/hip_runtime.h>
#include <math.h>

typedef __bf16 bf16x8 __attribute__((ext_vector_type(8)));
typedef __bf16 bf16x4 __attribute__((ext_vector_type(4)));
typedef float  f32x4  __attribute__((ext_vector_type(4)));
typedef float  f32x2  __attribute__((ext_vector_type(2)));
typedef unsigned long long u64x2 __attribute__((ext_vector_type(2)));

__device__ __forceinline__ float silu_f(float x){ return x / (1.f + __expf(-x)); }
__device__ __forceinline__ float sigm_f(float x){ return 1.f / (1.f + __expf(-x)); }

__device__ __forceinline__ float ntld_f(const float* p){
  return __builtin_nontemporal_load(p);
}
__device__ __forceinline__ float ntbf(const __bf16* p){
  unsigned short us = __builtin_nontemporal_load((const unsigned short*)p);
  union { unsigned u; float f; } cv; cv.u = ((unsigned)us) << 16;
  return cv.f;
}
__device__ __forceinline__ void nt_store_f(float* p, float v){
  __builtin_nontemporal_store(v, p);
}
__device__ __forceinline__ void nt_store_b8(__bf16* p, bf16x8 v){
  u64x2 u; __builtin_memcpy(&u, &v, 16);
  __builtin_nontemporal_store(u, (u64x2*)p);
}
__device__ __forceinline__ f32x2 b4lo(bf16x4 v){ f32x2 r; r[0]=(float)v[0]; r[1]=(float)v[1]; return r; }
__device__ __forceinline__ f32x2 b4hi(bf16x4 v){ f32x2 r; r[0]=(float)v[2]; r[1]=(float)v[3]; return r; }

// Block ranges: [0,nbPrep) W2->bf16 transpose; [nbPrep,+nbHist) dst histogram;
// rest: per-node attention vectors kv[n]=Wk@(nf@Wq+bq), c[n]=(nf@Wq+bq).bk
__global__ void __launch_bounds__(256) k_setup(const float* __restrict__ W2,
    __bf16* __restrict__ W2t, const int* __restrict__ ei, int* __restrict__ cnt,
    const float* __restrict__ nf, const float* __restrict__ Wq,
    const float* __restrict__ bq, const float* __restrict__ Wk,
    const float* __restrict__ bk, float* __restrict__ kvt, float* __restrict__ carr,
    int nbPrep, int nbHist, int N, int E){
  int b = blockIdx.x, t = threadIdx.x;
  if (b < nbPrep){
    int gid = b*256 + t;   // 163840 total
    int h = gid / 2560;
    int col = gid - h*2560;
    W2t[(size_t)(h>>5)*81920 + col*32 + (h&31)] = (__bf16)ntld_f(&W2[gid]);
    return;
  }
  if (b < nbPrep + nbHist){
    int e = (b - nbPrep)*256 + t;
    if (e < E) atomicAdd(&cnt[ei[E+e]], 1);
    return;
  }
  __shared__ float M[32][33];
  __shared__ float mb[32];
  __shared__ float nfl[64][33];
  __shared__ float bqbk_s;
  const int n0 = (b - nbPrep - nbHist)*64;
  for (int idx = t; idx < 1024; idx += 256){
    int s = idx >> 5, i = idx & 31;
    float acc = 0.f;
    #pragma unroll
    for (int j = 0; j < 8; ++j) acc += Wq[s*8+j]*Wk[i*8+j];
    M[s][i] = acc;
  }
  if (t < 32){
    float acc = 0.f;
    #pragma unroll
    for (int j = 0; j < 8; ++j) acc += Wq[t*8+j]*bk[j];
    mb[t] = acc;
  }
  if (t == 0){
    float acc = 0.f;
    #pragma unroll
    for (int j = 0; j < 8; ++j) acc += bq[j]*bk[j];
    bqbk_s = acc;
  }
  for (int idx = t; idx < 2048; idx += 256){
    int nl = idx >> 5, s = idx & 31;
    int n = n0 + nl;
    nfl[nl][s] = (n < N) ? nf[(size_t)n*80 + s] : 0.f;
  }
  __syncthreads();
  for (int idx = t; idx < 2048; idx += 256){
    int nl = idx >> 5, i = idx & 31;
    int n = n0 + nl;
    if (n < N){
      float acc = 0.f;
      #pragma unroll 8
      for (int s = 0; s < 32; ++s) acc += nfl[nl][s]*M[s][i];
      kvt[(size_t)n*32 + i] = acc;
    }
  }
  if (t < 64){
    int n = n0 + t;
    if (n < N){
      float acc = bqbk_s;
      #pragma unroll 8
      for (int s = 0; s < 32; ++s) acc += nfl[t][s]*mb[s];
      carr[n] = acc;
    }
  }
}

__global__ void __launch_bounds__(1024) k_scan(const int* __restrict__ cnt,
    int* __restrict__ cursor, float* __restrict__ bnacc, int N, int E){
  __shared__ int part[1024];
  int t = threadIdx.x;
  if (t < 80) bnacc[t] = 0.f;
  int chunk = (N + 1023) >> 10;
  int lo = t*chunk, hi = min(lo+chunk, N);
  int s = 0;
  for (int i = lo; i < hi; ++i) s += cnt[i];
  part[t] = s;
  __syncthreads();
  for (int off = 1; off < 1024; off <<= 1){
    int v = (t >= off) ? part[t-off] : 0;
    __syncthreads();
    part[t] += v;
    __syncthreads();
  }
  int base = (t == 0) ? 0 : part[t-1];
  for (int i = lo; i < hi; ++i){
    cursor[i] = base;
    base += cnt[i];
  }
}

// Per-edge precompute: u (bf16, MFMA-A tiled), coef tables cAB/cV (bf16),
// bias-sums biasS[e][32]/biasV[e][48] (f32), CSR perm. 64 edges/block.
__global__ void __launch_bounds__(256) k_prep(
    const float* __restrict__ nf, const int* __restrict__ ei,
    const float* __restrict__ sh, const float* __restrict__ radial,
    const float* __restrict__ W1, const float* __restrict__ b1,
    const float* __restrict__ b2, int* __restrict__ cursor,
    __bf16* __restrict__ uG, __bf16* __restrict__ cabG, __bf16* __restrict__ cvG,
    float* __restrict__ biasSG, float* __restrict__ biasVG,
    int* __restrict__ permG, int E, int NT)
{
  __shared__ float featT[80][65];
  __shared__ float radl[64][17];
  __shared__ float shlT[4][64];
  __shared__ float w1l[1024];
  __shared__ float b1l[64];
  __shared__ __align__(16) __bf16 u_l[64][72];
  __shared__ __align__(16) __bf16 cab_l[48][64];
  __shared__ __align__(16) __bf16 cv_l[64][3][64];
  __shared__ int src_l[64];

  const int t = threadIdx.x;
  const int e0 = blockIdx.x*64;
  const int tg0 = blockIdx.x*4;

  if (t < 64){
    int ee = e0 + t;
    if (ee < E){
      src_l[t] = ei[ee];
      permG[ee] = atomicAdd(&cursor[ei[(size_t)E+ee]], 1);
    } else src_l[t] = ei[E-1];
    b1l[t] = b1[t];
  }
  {
    int e = t >> 2, c = t & 3;
    int ec = min(e0+e, E-1);
    shlT[c][e] = ntld_f(&sh[(size_t)ec*4+c]);
  }
  for (int i = t; i < 1024; i += 256){
    int e = i >> 4, r = i & 15;
    int ec = min(e0+e, E-1);
    radl[e][r] = ntld_f(&radial[(size_t)ec*16+r]);
  }
  *(float4*)&w1l[t*4] = ((const float4*)W1)[t];
  __syncthreads();

  for (int i = t; i < 5120; i += 256){
    int e = i / 80, idx = i - e*80;
    featT[idx][e] = nf[(size_t)src_l[e]*80 + idx];
  }
  for (int i = t; i < 4096; i += 256){
    int e = i & 63, h = i >> 6;
    float acc = b1l[h];
    #pragma unroll
    for (int r = 0; r < 16; ++r) acc += radl[e][r]*w1l[r*64+h];
    u_l[e][h] = (__bf16)silu_f(acc);
  }
  __syncthreads();

  const float inv_s3 = 0.57735026918962576f;
  const float inv_s2 = 0.70710678118654752f;
  const float a0 = 0.14433756729740643f;  // 1/sqrt(48)
  const float a1 = 0.125f;                // 1/sqrt(64)

  for (int i = t; i < 3072; i += 256){
    int r = i >> 6, e = i & 63;
    float val;
    if (r < 32) val = a0 * shlT[0][e] * featT[r][e];
    else {
      int v = r - 32;
      float dot = (featT[32+v*3][e]*shlT[1][e] + featT[33+v*3][e]*shlT[2][e]
                 + featT[34+v*3][e]*shlT[3][e]) * inv_s3;
      val = a0 * dot;
    }
    cab_l[r][e] = (__bf16)val;
  }
  for (int i = t; i < 12288; i += 256){
    int e = i & 63, r = (i >> 6) & 63, c = i >> 12;
    float val;
    if (r < 32) val = a1 * shlT[1+c][e] * featT[r][e];
    else if (r < 48){
      int v = r - 32;
      val = a1 * shlT[0][e] * featT[32+v*3+c][e];
    } else {
      int v = r - 48;
      int c1 = c+1; if (c1 > 2) c1 -= 3;
      int c2 = c+2; if (c2 > 2) c2 -= 3;
      val = a1 * inv_s2 * (featT[32+v*3+c1][e]*shlT[1+c2][e]
                         - featT[32+v*3+c2][e]*shlT[1+c1][e]);
    }
    cv_l[r][c][e] = (__bf16)val;
  }
  __syncthreads();   // featT dead from here (b2 stages into its space)

  // ---- tiled outputs (16 edges per tile; tile layouts match k_edge lanes)
  for (int i = t; i < 512; i += 256){
    int tl = i >> 7, rem = i & 127, k8 = rem >> 4, e = rem & 15;
    if (tg0 + tl < NT){
      bf16x8 v = *(const bf16x8*)&u_l[tl*16 + e][k8*8];
      *(bf16x8*)((char*)uG + (size_t)(tg0+tl)*2048 + k8*256 + e*16) = v;
    }
  }
  for (int i = t; i < 384; i += 256){
    int tl = i / 96, rem = i - tl*96, r = rem >> 1, h = rem & 1;
    if (tg0 + tl < NT){
      bf16x8 v = *(const bf16x8*)&cab_l[r][tl*16 + h*8];
      *(bf16x8*)((char*)cabG + (size_t)(tg0+tl)*1536 + r*32 + h*16) = v;
    }
  }
  for (int i = t; i < 1536; i += 256){
    int tl = i / 384, rem = i - tl*384, r = rem / 6, rem2 = rem - r*6,
        c = rem2 >> 1, h = rem2 & 1;
    if (tg0 + tl < NT){
      bf16x8 v = *(const bf16x8*)&cv_l[r][c][tl*16 + h*8];
      *(bf16x8*)((char*)cvG + (size_t)(tg0+tl)*6144 + r*96 + c*32 + h*16) = v;
    }
  }
  // ---- stage b2 into dead featT space, then bias-sum matvecs
  float* b2s = &featT[0][0];
  for (int i = t; i < 2560; i += 256) b2s[i] = b2[i];
  __syncthreads();
  // biasS[e][k] = sum_r cab[e][r] * b2[(2r + (k>=16))*16 + (k&15)]
  for (int i = t; i < 2048; i += 256){
    int e = i >> 5, k = i & 31;
    int hi = k >> 4, kk = k & 15;
    float acc = 0.f;
    #pragma unroll 8
    for (int r = 0; r < 48; ++r)
      acc += (float)cab_l[r][e] * b2s[(2*r+hi)*16 + kk];
    int tl = e >> 4, et = e & 15;
    if (tg0 + tl < NT)
      biasSG[(size_t)(tg0+tl)*512 + et*32 + k] = acc;
  }
  // biasV[e][w*3+c] = sum_r cv[e][r][c] * b2[(96+r)*16 + w]
  for (int i = t; i < 3072; i += 256){
    int e = i / 48, col = i - (i/48)*48;
    int w = col/3, c = col - w*3;
    float acc = 0.f;
    #pragma unroll 8
    for (int r = 0; r < 64; ++r)
      acc += (float)cv_l[r][c][e] * b2s[(96+r)*16 + w];
    int tl = e >> 4, et = e & 15;
    if (tg0 + tl < NT)
      biasVG[(size_t)(tg0+tl)*768 + et*48 + col] = acc;
  }
}

// Panel stored quad-major: conflict-free ds_read_b128 (R8-verified)
#define LOAD_PANEL(BASE_IT, NITS) do {                                         \
    for (int idx = t; idx < (NITS)*128; idx += 1024){                          \
      int itl_ = idx >> 7, rem_ = idx & 127, half_ = rem_ >> 6, r6_ = rem_ & 63;\
      int col_ = r6_ >> 2, quad_ = r6_ & 3;                                    \
      *(float4*)(panel + itl_*2048 + half_*1024 + quad_*256 + col_*16) =       \
        *(const float4*)(w2b + half_*163840 + (size_t)((BASE_IT)+itl_)*1024    \
                         + col_*64 + quad_*16);                                \
    }                                                                          \
  } while(0)

// stage both tiles' cab interleaved: myCab[r*64 + q*16] = [A 8B | B 8B]
#define CAB_STAGE2() do {                                                      \
    for (int i = lane; i < 384; i += 64){                                      \
      int tb_ = i & 1; int c_ = i >> 1;                                        \
      int r_ = c_ >> 2, q_ = c_ & 3;                                           \
      const char* s_ = cabGb + (size_t)(tb_ ? cB : cA)*1536 + r_*32 + q_*8;    \
      unsigned long long v_ = *(const unsigned long long*)s_;                  \
      *(unsigned long long*)(myCab + r_*64 + q_*16 + tb_*8) = v_;              \
    }                                                                          \
  } while(0)

// stage 16 cv rows of (HALF,SUB) packed: q01A@0, q01B@1024, q2AB@2048
#define CV_STAGE2(SUB, HALF) do {                                              \
    for (int i = lane; i < 384; i += 64){                                      \
      int tb_ = i & 1; int x_ = i >> 1;                                        \
      int c3_ = x_ % 3; int rem_ = x_ / 3;                                     \
      int il_ = rem_ >> 2, q_ = rem_ & 3;                                      \
      const char* s_ = cvGb + (size_t)(tb_ ? cB : cA)*6144 + (HALF)*3072       \
                     + ((SUB)*16 + il_)*96 + c3_*32 + q_*8;                    \
      unsigned long long v_ = *(const unsigned long long*)s_;                  \
      char* d_ = (c3_ < 2) ? (myCab + tb_*1024 + il_*64 + q_*16 + c3_*8)       \
                           : (myCab + 2048 + il_*64 + q_*16 + tb_*8);          \
      *(unsigned long long*)d_ = v_;                                           \
    }                                                                          \
  } while(0)

// One S pair-loop over the resident 48-it panel; no bias (precomputed),
// single b128 coef read covers both tiles.
#define S_PAIR(SECOND, TA, TB) do {                                            \
    _Pragma("unroll 4")                                                        \
    for (int itl = 0; itl < 48; ++itl){                                        \
      bf16x8 B0_ = *(const bf16x8*)(panel + itl*2048 + laneOff);               \
      bf16x8 B1_ = *(const bf16x8*)(panel + itl*2048 + 1024 + laneOff);        \
      f32x4 dA_; dA_[0]=0;dA_[1]=0;dA_[2]=0;dA_[3]=0; f32x4 dB_ = dA_;         \
      dA_ = __builtin_amdgcn_mfma_f32_16x16x32_bf16(u##TA##_0, B0_, dA_, 0,0,0);\
      dB_ = __builtin_amdgcn_mfma_f32_16x16x32_bf16(u##TB##_0, B0_, dB_, 0,0,0);\
      dA_ = __builtin_amdgcn_mfma_f32_16x16x32_bf16(u##TA##_1, B1_, dA_, 0,0,0);\
      dB_ = __builtin_amdgcn_mfma_f32_16x16x32_bf16(u##TB##_1, B1_, dB_, 0,0,0);\
      f32x2 dAlo_ = __builtin_shufflevector(dA_,dA_,0,1);                      \
      f32x2 dAhi_ = __builtin_shufflevector(dA_,dA_,2,3);                      \
      f32x2 dBlo_ = __builtin_shufflevector(dB_,dB_,0,1);                      \
      f32x2 dBhi_ = __builtin_shufflevector(dB_,dB_,2,3);                      \
      const int r_ = (SECOND)*24 + (itl>>1);                                   \
      bf16x8 c8_ = *(const bf16x8*)(myCab + r_*64 + quad*16);                  \
      bf16x4 cA_ = __builtin_shufflevector(c8_, c8_, 0,1,2,3);                 \
      bf16x4 cB_ = __builtin_shufflevector(c8_, c8_, 4,5,6,7);                 \
      if (itl & 1){                                                            \
        s1l##TA += b4lo(cA_)*dAlo_; s1h##TA += b4hi(cA_)*dAhi_;                \
        s1l##TB += b4lo(cB_)*dBlo_; s1h##TB += b4hi(cB_)*dBhi_;                \
      } else {                                                                 \
        s0l##TA += b4lo(cA_)*dAlo_; s0h##TA += b4hi(cA_)*dAhi_;                \
        s0l##TB += b4lo(cB_)*dBlo_; s0h##TB += b4hi(cB_)*dBhi_;                \
      }                                                                        \
    }                                                                          \
  } while(0)

// One V pair-sub-loop: 16 panel its; coef reads = 3 b128 (both tiles).
#define V_PAIR_SUB(SUB, TA, TB) do {                                           \
    _Pragma("unroll 4")                                                        \
    for (int il = 0; il < 16; ++il){                                           \
      const int gitl = (SUB)*16 + il;                                          \
      bf16x8 B0_ = *(const bf16x8*)(panel + gitl*2048 + laneOff);              \
      bf16x8 B1_ = *(const bf16x8*)(panel + gitl*2048 + 1024 + laneOff);       \
      f32x4 dA_; dA_[0]=0;dA_[1]=0;dA_[2]=0;dA_[3]=0; f32x4 dB_ = dA_;         \
      dA_ = __builtin_amdgcn_mfma_f32_16x16x32_bf16(u##TA##_0, B0_, dA_, 0,0,0);\
      dB_ = __builtin_amdgcn_mfma_f32_16x16x32_bf16(u##TB##_0, B0_, dB_, 0,0,0);\
      dA_ = __builtin_amdgcn_mfma_f32_16x16x32_bf16(u##TA##_1, B1_, dA_, 0,0,0);\
      dB_ = __builtin_amdgcn_mfma_f32_16x16x32_bf16(u##TB##_1, B1_, dB_, 0,0,0);\
      f32x2 dAlo_ = __builtin_shufflevector(dA_,dA_,0,1);                      \
      f32x2 dAhi_ = __builtin_shufflevector(dA_,dA_,2,3);                      \
      f32x2 dBlo_ = __builtin_shufflevector(dB_,dB_,0,1);                      \
      f32x2 dBhi_ = __builtin_shufflevector(dB_,dB_,2,3);                      \
      bf16x8 cA01_ = *(const bf16x8*)(myCab + il*64 + quad*16);                \
      bf16x8 cB01_ = *(const bf16x8*)(myCab + 1024 + il*64 + quad*16);         \
      bf16x8 c2_   = *(const bf16x8*)(myCab + 2048 + il*64 + quad*16);         \
      bf16x4 q0A_ = __builtin_shufflevector(cA01_, cA01_, 0,1,2,3);            \
      bf16x4 q1A_ = __builtin_shufflevector(cA01_, cA01_, 4,5,6,7);            \
      bf16x4 q0B_ = __builtin_shufflevector(cB01_, cB01_, 0,1,2,3);            \
      bf16x4 q1B_ = __builtin_shufflevector(cB01_, cB01_, 4,5,6,7);            \
      bf16x4 q2A_ = __builtin_shufflevector(c2_, c2_, 0,1,2,3);                \
      bf16x4 q2B_ = __builtin_shufflevector(c2_, c2_, 4,5,6,7);                \
      v0l##TA += b4lo(q0A_)*dAlo_; v0h##TA += b4hi(q0A_)*dAhi_;                \
      v1l##TA += b4lo(q1A_)*dAlo_; v1h##TA += b4hi(q1A_)*dAhi_;                \
      v2l##TA += b4lo(q2A_)*dAlo_; v2h##TA += b4hi(q2A_)*dAhi_;                \
      v0l##TB += b4lo(q0B_)*dBlo_; v0h##TB += b4hi(q0B_)*dBhi_;                \
      v1l##TB += b4lo(q1B_)*dBlo_; v1h##TB += b4hi(q1B_)*dBhi_;                \
      v2l##TB += b4lo(q2B_)*dBlo_; v2h##TB += b4hi(q2B_)*dBhi_;                \
    }                                                                          \
  } while(0)

#define S_FLUSH(TG, S0LO, S0HI, S1LO, S1HI) do {                               \
      myOut[(eb+0)*56 + nlo] = S0LO[0];                                        \
      myOut[(eb+1)*56 + nlo] = S0LO[1];                                        \
      myOut[(eb+2)*56 + nlo] = S0HI[0];                                        \
      myOut[(eb+3)*56 + nlo] = S0HI[1];                                        \
      myOut[(eb+0)*56 + 16+nlo] = S1LO[0];                                     \
      myOut[(eb+1)*56 + 16+nlo] = S1LO[1];                                     \
      myOut[(eb+2)*56 + 16+nlo] = S1HI[0];                                     \
      myOut[(eb+3)*56 + 16+nlo] = S1HI[1];                                     \
      const int e0e = (TG)*16;                                                 \
      { int e = lane>>2, seg = lane&3, eg = e0e + e;                           \
        if (eg < E){                                                           \
          const float* bS_ = biasSG + (size_t)(TG)*512 + lane*8;               \
          f32x4 m0 = *(const f32x4*)&myOut[e*56 + seg*8]     + *(const f32x4*)bS_;\
          f32x4 m1 = *(const f32x4*)&myOut[e*56 + seg*8 + 4] + *(const f32x4*)(bS_+4);\
          bf16x8 o; o[0]=(__bf16)m0[0]; o[1]=(__bf16)m0[1];                    \
          o[2]=(__bf16)m0[2]; o[3]=(__bf16)m0[3]; o[4]=(__bf16)m1[0];          \
          o[5]=(__bf16)m1[1]; o[6]=(__bf16)m1[2]; o[7]=(__bf16)m1[3];          \
          nt_store_b8(msgs + (size_t)permG[eg]*80 + seg*8, o);                 \
        } }                                                                    \
      for (int r8 = 0; r8 < 2; ++r8){                                          \
        int e = r8*8 + (lane>>3), kq = lane&7, eg = e0e + e;                   \
        f32x4 ms = *(const f32x4*)&myOut[e*56 + kq*4];                         \
        ms += *(const f32x4*)(biasSG + (size_t)(TG)*512 + r8*256 + lane*4);    \
        int dn = ei[(size_t)E + min(eg, E-1)];                                 \
        const float* kvp = kvt + (size_t)dn*32 + kq*4;                         \
        float part = ms[0]*kvp[0]+ms[1]*kvp[1]+ms[2]*kvp[2]+ms[3]*kvp[3];      \
        part += __shfl_xor(part, 1);                                           \
        part += __shfl_xor(part, 2);                                           \
        part += __shfl_xor(part, 4);                                           \
        if (kq == 0 && eg < E){                                                \
          float lg = (part + carr[dn]) * 0.35355339059327373f                  \
                   + logf(ntld_f(&env[eg]) + 1e-8f);                           \
          nt_store_f(&logits_s[permG[eg]], lg);                                \
        } }                                                                    \
  } while(0)

#define V_FLUSH(TG, V0LO, V0HI, V1LO, V1HI, V2LO, V2HI) do {                   \
      const int cb2 = nlo*3;                                                   \
      myOut[(eb+0)*56 + cb2+0] = V0LO[0];                                      \
      myOut[(eb+1)*56 + cb2+0] = V0LO[1];                                      \
      myOut[(eb+2)*56 + cb2+0] = V0HI[0];                                      \
      myOut[(eb+3)*56 + cb2+0] = V0HI[1];                                      \
      myOut[(eb+0)*56 + cb2+1] = V1LO[0];                                      \
      myOut[(eb+1)*56 + cb2+1] = V1LO[1];                                      \
      myOut[(eb+2)*56 + cb2+1] = V1HI[0];                                      \
      myOut[(eb+3)*56 + cb2+1] = V1HI[1];                                      \
      myOut[(eb+0)*56 + cb2+2] = V2LO[0];                                      \
      myOut[(eb+1)*56 + cb2+2] = V2LO[1];                                      \
      myOut[(eb+2)*56 + cb2+2] = V2HI[0];                                      \
      myOut[(eb+3)*56 + cb2+2] = V2HI[1];                                      \
      const int e0e = (TG)*16;                                                 \
      for (int i = lane; i < 96; i += 64){                                     \
        int e = i/6, seg = i - (i/6)*6, eg = e0e + e;                          \
        if (eg < E){                                                           \
          const float* bV_ = biasVG + (size_t)(TG)*768 + i*8;                  \
          f32x4 m0 = *(const f32x4*)&myOut[e*56 + seg*8]     + *(const f32x4*)bV_;\
          f32x4 m1 = *(const f32x4*)&myOut[e*56 + seg*8 + 4] + *(const f32x4*)(bV_+4);\
          bf16x8 o; o[0]=(__bf16)m0[0]; o[1]=(__bf16)m0[1];                    \
          o[2]=(__bf16)m0[2]; o[3]=(__bf16)m0[3]; o[4]=(__bf16)m1[0];          \
          o[5]=(__bf16)m1[1]; o[6]=(__bf16)m1[2]; o[7]=(__bf16)m1[3];          \
          nt_store_b8(msgs + (size_t)permG[eg]*80 + 32 + seg*8, o);            \
        } }                                                                    \
  } while(0)

// Persistent-panel edge kernel: 256 blocks x 1024 threads (4 waves/SIMD).
// Bias precomputed (no b2 in loop); coef reads packed to b128 (S: 1 read,
// V: 3 reads for both tiles). LDS = 96K panel + 56K wstage = 152 KB.
__global__ void __launch_bounds__(1024, 4) k_edge(
    const __bf16* __restrict__ W2t,
    const __bf16* __restrict__ uG, const __bf16* __restrict__ cabG,
    const __bf16* __restrict__ cvG,
    const float* __restrict__ biasSG, const float* __restrict__ biasVG,
    const int* __restrict__ ei,
    const int* __restrict__ permG, const float* __restrict__ kvt,
    const float* __restrict__ carr, const float* __restrict__ env,
    __bf16* __restrict__ msgs, float* __restrict__ logits_s, int E, int NT)
{
  __shared__ __align__(16) char panel[98304];      // 48 its x 2048 B (swizzled)
  __shared__ __align__(16) char wstage[16][3584];  // per wave: coef stage / out alias

  const int t = threadIdx.x;
  const int lane = t & 63;
  const int wv   = t >> 6;
  const int quad = lane >> 4;
  const int nlo  = lane & 15;
  const int wgid = blockIdx.x*16 + wv;
  const int laneOff = quad*256 + nlo*16;
  const int uOff    = quad*256 + nlo*16;
  char*  myCab = wstage[wv];
  float* myOut = (float*)wstage[wv];      // aliases coef stage (flush after loops only)
  const char* w2b   = (const char*)W2t;
  const char* uGb   = (const char*)uG;
  const char* cabGb = (const char*)cabG;
  const char* cvGb  = (const char*)cvG;

  const int tA = wgid, tB = wgid + 4096;
  const bool hA = tA < NT, hB = tB < NT;
  const int cA = min(tA, NT-1), cB = min(tB, NT-1);

  // ---- hoisted u fragments (used in all 4 phases)
  const bf16x8 uA_0 = *(const bf16x8*)(uGb + (size_t)cA*2048 + uOff);
  const bf16x8 uA_1 = *(const bf16x8*)(uGb + (size_t)cA*2048 + 1024 + uOff);
  const bf16x8 uB_0 = *(const bf16x8*)(uGb + (size_t)cB*2048 + uOff);
  const bf16x8 uB_1 = *(const bf16x8*)(uGb + (size_t)cB*2048 + 1024 + uOff);

  // ---- S partials (registers, live S0->S1)
  f32x2 s0lA={0,0}, s0hA={0,0}, s1lA={0,0}, s1hA={0,0};
  f32x2 s0lB={0,0}, s0hB={0,0}, s1lB={0,0}, s1hB={0,0};

  const int eb = quad*4;

  // ---- S phases: cab staged ONCE (packed, both tiles), reused in S1
  LOAD_PANEL(0, 48);
  CAB_STAGE2();
  __syncthreads();
  S_PAIR(0, A, B);
  __syncthreads();
  LOAD_PANEL(48, 48);
  __syncthreads();
  S_PAIR(1, A, B);
  if (hA) S_FLUSH(tA, s0lA, s0hA, s1lA, s1hA);
  if (hB) S_FLUSH(tB, s0lB, s0hB, s1lB, s1hB);
  __syncthreads();

  // ---- V partials (registers, live V0->V1)
  f32x2 v0lA={0,0}, v0hA={0,0}, v1lA={0,0}, v1hA={0,0}, v2lA={0,0}, v2hA={0,0};
  f32x2 v0lB={0,0}, v0hB={0,0}, v1lB={0,0}, v1hB={0,0}, v2lB={0,0}, v2hB={0,0};

  LOAD_PANEL(96, 32);
  __syncthreads();
  CV_STAGE2(0, 0);
  V_PAIR_SUB(0, A, B);
  CV_STAGE2(1, 0);
  V_PAIR_SUB(1, A, B);
  __syncthreads();
  LOAD_PANEL(128, 32);
  __syncthreads();
  CV_STAGE2(0, 1);
  V_PAIR_SUB(0, A, B);
  CV_STAGE2(1, 1);
  V_PAIR_SUB(1, A, B);
  if (hA) V_FLUSH(tA, v0lA, v0hA, v1lA, v1hA, v2lA, v2hA);
  if (hB) V_FLUSH(tB, v0lB, v0hB, v1lB, v1hB, v2lB, v2hB);
}

// One wave per node: max pass, merged gather+den pass (bf16 msgs, NT loads),
// fused node matmuls + gate + residual + BN stats.
__global__ void __launch_bounds__(256) k_agg(
    const __bf16* __restrict__ msgs, const float* __restrict__ logits_s,
    const int* __restrict__ cursor, const float* __restrict__ nf,
    const float* __restrict__ Wout_s, const float* __restrict__ Wout_v,
    const float* __restrict__ Wg_s, const float* __restrict__ Wg_v,
    float* __restrict__ xbuf, float* __restrict__ bnacc, int N)
{
  __shared__ float aggl[4][80];
  __shared__ float t1[4][96];
  __shared__ float t2[4][96];
  __shared__ float bnl[80];
  const int t = threadIdx.x, l = t & 63, wv = t >> 6;
  const int n = blockIdx.x*4 + wv;
  const bool act = (n < N);
  const int nc = act ? n : (N-1);
  if (t < 80) bnl[t] = 0.f;

  const int r0 = (nc == 0) ? 0 : cursor[nc-1];
  const int r1 = cursor[nc];
  const int deg = act ? (r1 - r0) : 0;

  float mym = -3.4e38f;
  for (int i = l; i < deg; i += 64) mym = fmaxf(mym, logits_s[r0+i]);
  #pragma unroll
  for (int s = 32; s; s >>= 1) mym = fmaxf(mym, __shfl_xor(mym, s));
  float denp = 0.f, acc0 = 0.f, acc1 = 0.f;
  for (int c0 = 0; c0 < deg; c0 += 64){
    const int len = min(64, deg - c0);
    float ex = 0.f;
    if (l < len) ex = __expf(logits_s[r0+c0+l] - mym);
    denp += ex;
    for (int j0 = 0; j0 < len; j0 += 4){
      const int jn = len - j0;
      const __bf16* base = msgs + (size_t)(r0+c0+j0)*80;
      float v0=0,v1=0,v2=0,v3=0, w0=0,w1=0,w2=0,w3=0;
      float a0_=0,a1_=0,a2_=0,a3_=0;
      v0 = ntbf(&base[l]); if (l < 16) w0 = ntbf(&base[64+l]); a0_ = __shfl(ex, j0);
      if (jn > 1){ v1 = ntbf(&base[80+l]);  if (l < 16) w1 = ntbf(&base[144+l]); a1_ = __shfl(ex, j0+1); }
      if (jn > 2){ v2 = ntbf(&base[160+l]); if (l < 16) w2 = ntbf(&base[224+l]); a2_ = __shfl(ex, j0+2); }
      if (jn > 3){ v3 = ntbf(&base[240+l]); if (l < 16) w3 = ntbf(&base[304+l]); a3_ = __shfl(ex, j0+3); }
      acc0 += a0_*v0 + a1_*v1 + a2_*v2 + a3_*v3;
      if (l < 16) acc1 += a0_*w0 + a1_*w1 + a2_*w2 + a3_*w3;
    }
  }
  #pragma unroll
  for (int s = 32; s; s >>= 1) denp += __shfl_xor(denp, s);
  const float inv = 1.f/(denp + 1e-8f);
  aggl[wv][l] = acc0 * inv;
  if (l < 16) aggl[wv][64+l] = acc1 * inv;
  __syncthreads();

  const float* arow = &aggl[wv][0];
  const float iS = 0.17677669529663687f;  // 1/sqrt(32)
  const float iV = 0.25f;                 // 1/sqrt(16)
  for (int o = l; o < 80; o += 64){
    float val = 0.f;
    if (o < 32){
      for (int s = 0; s < 32; ++s) val += arow[s]*Wout_s[s*32+o];
      val *= iS;
    } else {
      int w = (o-32)/3, c = (o-32)-w*3;
      for (int v = 0; v < 16; ++v) val += arow[32+v*3+c]*Wout_v[v*16+w];
      val *= iV;
    }
    t1[wv][o] = val;
  }
  __syncthreads();
  for (int o = l; o < 96; o += 64){
    float val = 0.f;
    if (o < 48){
      for (int k = 0; k < 32; ++k) val += t1[wv][k]*Wg_s[k*48+o];
      val *= iS;
    } else {
      int w = (o-48)/3, c = (o-48)-w*3;
      for (int v = 0; v < 16; ++v) val += t1[wv][32+v*3+c]*Wg_v[v*16+w];
      val *= iV;
    }
    t2[wv][o] = val;
  }
  __syncthreads();
  for (int o = l; o < 80; o += 64){
    float x;
    if (o < 32){
      x = silu_f(t2[wv][o]) + nf[(size_t)nc*80+o];
      if (act){
        nt_store_f(&xbuf[(size_t)n*80+o], x);
        atomicAdd(&bnl[o], x);
        atomicAdd(&bnl[32+o], x*x);
      }
    } else {
      int w = (o-32)/3;
      x = sigm_f(t2[wv][32+w]) * t2[wv][48+(o-32)] + nf[(size_t)nc*80+o];
      if (act){
        nt_store_f(&xbuf[(size_t)n*80+o], x);
        atomicAdd(&bnl[64+w], x*x);
      }
    }
  }
  __syncthreads();
  if (t < 80) atomicAdd(&bnacc[t], bnl[t]);
}

__global__ void __launch_bounds__(256) k_out(const float* __restrict__ xbuf,
    const float* __restrict__ bnacc,
    const float* __restrict__ bn_ws, const float* __restrict__ bn_bs,
    const float* __restrict__ bn_wv, float* __restrict__ out, int N){
  __shared__ float coef[80];
  int t = threadIdx.x;
  float fN = (float)N;
  if (t < 32){
    float mean = bnacc[t]/fN;
    float var = bnacc[32+t]/fN - mean*mean;
    float cm = bn_ws[t]*rsqrtf(var + 1e-5f);
    coef[t] = cm;
    coef[32+t] = bn_bs[t] - mean*cm;
  } else if (t < 48){
    int v = t - 32;
    coef[64+v] = bn_wv[v]*rsqrtf(bnacc[64+v]/(3.f*fN) + 1e-5f);
  }
  __syncthreads();
  int i = blockIdx.x*256 + t;
  if (i >= N*80) return;
  int o = i - (i/80)*80;
  float x = ntld_f(&xbuf[i]);
  nt_store_f(&out[i], (o < 32) ? (x*coef[o] + coef[32+o]) : (x*coef[64+(o-32)/3]));
}

extern "C" void kernel_launch(void* const* d_in, const int* in_sizes, int n_in,
                              void* d_out, int out_size, void* d_ws, size_t ws_size,
                              hipStream_t stream) {
  const float* nf     = (const float*)d_in[0];
  const int*   ei     = (const int*)  d_in[1];
  const float* sh     = (const float*)d_in[2];
  const float* radial = (const float*)d_in[3];
  const float* env    = (const float*)d_in[4];
  const float* W1     = (const float*)d_in[5];
  const float* b1     = (const float*)d_in[6];
  const float* W2     = (const float*)d_in[7];
  const float* b2     = (const float*)d_in[8];
  const float* Wq     = (const float*)d_in[9];
  const float* bq     = (const float*)d_in[10];
  const float* Wk     = (const float*)d_in[11];
  const float* bk     = (const float*)d_in[12];
  const float* Wout_s = (const float*)d_in[13];
  const float* Wout_v = (const float*)d_in[14];
  const float* Wg_s   = (const float*)d_in[15];
  const float* Wg_v   = (const float*)d_in[16];
  const float* bn_ws  = (const float*)d_in[17];
  const float* bn_bs  = (const float*)d_in[18];
  const float* bn_wv  = (const float*)d_in[19];

  const int E = in_sizes[4];
  const int N = in_sizes[0] / 80;
  const int NT = (E + 15)/16;

  float* ws = (float*)d_ws;
  size_t off = 0;
  __bf16* w2t    = (__bf16*)(ws + off); off += 81920;          // 320 KB bf16
  __bf16* msgs   = (__bf16*)(ws + off); off += (size_t)E*40;   // E*80 bf16
  float* logits_s= ws + off; off += E;
  int* cnt       = (int*)(ws + off); off += N;
  int* cursor    = (int*)(ws + off); off += N;
  float* xbuf    = ws + off; off += (size_t)N*80;
  float* bnacc   = ws + off; off += 80;
  float* kvt     = ws + off; off += (size_t)N*32;
  float* carr    = ws + off; off += N;
  int* permG     = (int*)(ws + off); off += E;
  __bf16* uG     = (__bf16*)(ws + off); off += (size_t)NT*512;   // NT*2048 B
  __bf16* cabG   = (__bf16*)(ws + off); off += (size_t)NT*384;   // NT*1536 B
  __bf16* cvG    = (__bf16*)(ws + off); off += (size_t)NT*1536;  // NT*6144 B
  float* biasSG  = ws + off; off += (size_t)NT*512;              // NT*2048 B
  float* biasVG  = ws + off; off += (size_t)NT*768;              // NT*3072 B

  hipMemsetAsync(cnt, 0, (size_t)N*sizeof(int), stream);

  const int nbPrep = 640;                 // 163840/256
  const int nbHist = (E + 255)/256;
  const int nbKv   = (N + 63)/64;
  k_setup<<<nbPrep + nbHist + nbKv, 256, 0, stream>>>(W2, w2t, ei, cnt,
      nf, Wq, bq, Wk, bk, kvt, carr, nbPrep, nbHist, N, E);
  k_scan<<<1, 1024, 0, stream>>>(cnt, cursor, bnacc, N, E);
  k_prep<<<(E + 63)/64, 256, 0, stream>>>(nf, ei, sh, radial, W1, b1, b2,
      cursor, uG, cabG, cvG, biasSG, biasVG, permG, E, NT);
  k_edge<<<256, 1024, 0, stream>>>(w2t, uG, cabG, cvG, biasSG, biasVG,
      ei, permG, kvt, carr, env, msgs, logits_s, E, NT);
  k_agg<<<(N + 3)/4, 256, 0, stream>>>(msgs, logits_s, cursor, nf,
      Wout_s, Wout_v, Wg_s, Wg_v, xbuf, bnacc, N);
  k_out<<<(N*80 + 255)/256, 256, 0, stream>>>(xbuf, bnacc, bn_ws, bn_bs, bn_wv,
      (float*)d_out, N);
}

// Round 13
// 358.295 us; speedup vs baseline: 1.2227x; 1.2227x over previous
//
#include <hip/hip_runtime.h>
#include <math.h>

typedef __bf16 bf16x8 __attribute__((ext_vector_type(8)));
typedef __bf16 bf16x4 __attribute__((ext_vector_type(4)));
typedef float  f32x4  __attribute__((ext_vector_type(4)));
typedef float  f32x2  __attribute__((ext_vector_type(2)));
typedef unsigned long long u64x2 __attribute__((ext_vector_type(2)));

__device__ __forceinline__ float silu_f(float x){ return x / (1.f + __expf(-x)); }
__device__ __forceinline__ float sigm_f(float x){ return 1.f / (1.f + __expf(-x)); }

__device__ __forceinline__ float ntld_f(const float* p){
  return __builtin_nontemporal_load(p);
}
__device__ __forceinline__ float ntbf(const __bf16* p){
  unsigned short us = __builtin_nontemporal_load((const unsigned short*)p);
  union { unsigned u; float f; } cv; cv.u = ((unsigned)us) << 16;
  return cv.f;
}
__device__ __forceinline__ void nt_store_f(float* p, float v){
  __builtin_nontemporal_store(v, p);
}
__device__ __forceinline__ void nt_store_b8(__bf16* p, bf16x8 v){
  u64x2 u; __builtin_memcpy(&u, &v, 16);
  __builtin_nontemporal_store(u, (u64x2*)p);
}
__device__ __forceinline__ f32x2 b4lo(bf16x4 v){ f32x2 r; r[0]=(float)v[0]; r[1]=(float)v[1]; return r; }
__device__ __forceinline__ f32x2 b4hi(bf16x4 v){ f32x2 r; r[0]=(float)v[2]; r[1]=(float)v[3]; return r; }

// Block ranges: [0,nbPrep) W2->bf16 transpose; [nbPrep,+nbHist) dst histogram;
// rest: per-node attention vectors kv[n]=Wk@(nf@Wq+bq), c[n]=(nf@Wq+bq).bk
__global__ void __launch_bounds__(256) k_setup(const float* __restrict__ W2,
    __bf16* __restrict__ W2t, const int* __restrict__ ei, int* __restrict__ cnt,
    const float* __restrict__ nf, const float* __restrict__ Wq,
    const float* __restrict__ bq, const float* __restrict__ Wk,
    const float* __restrict__ bk, float* __restrict__ kvt, float* __restrict__ carr,
    int nbPrep, int nbHist, int N, int E){
  int b = blockIdx.x, t = threadIdx.x;
  if (b < nbPrep){
    int gid = b*256 + t;   // 163840 total
    int h = gid / 2560;
    int col = gid - h*2560;
    W2t[(size_t)(h>>5)*81920 + col*32 + (h&31)] = (__bf16)ntld_f(&W2[gid]);
    return;
  }
  if (b < nbPrep + nbHist){
    int e = (b - nbPrep)*256 + t;
    if (e < E) atomicAdd(&cnt[ei[E+e]], 1);
    return;
  }
  __shared__ float M[32][33];
  __shared__ float mb[32];
  __shared__ float nfl[64][33];
  __shared__ float bqbk_s;
  const int n0 = (b - nbPrep - nbHist)*64;
  for (int idx = t; idx < 1024; idx += 256){
    int s = idx >> 5, i = idx & 31;
    float acc = 0.f;
    #pragma unroll
    for (int j = 0; j < 8; ++j) acc += Wq[s*8+j]*Wk[i*8+j];
    M[s][i] = acc;
  }
  if (t < 32){
    float acc = 0.f;
    #pragma unroll
    for (int j = 0; j < 8; ++j) acc += Wq[t*8+j]*bk[j];
    mb[t] = acc;
  }
  if (t == 0){
    float acc = 0.f;
    #pragma unroll
    for (int j = 0; j < 8; ++j) acc += bq[j]*bk[j];
    bqbk_s = acc;
  }
  for (int idx = t; idx < 2048; idx += 256){
    int nl = idx >> 5, s = idx & 31;
    int n = n0 + nl;
    nfl[nl][s] = (n < N) ? nf[(size_t)n*80 + s] : 0.f;
  }
  __syncthreads();
  for (int idx = t; idx < 2048; idx += 256){
    int nl = idx >> 5, i = idx & 31;
    int n = n0 + nl;
    if (n < N){
      float acc = 0.f;
      #pragma unroll 8
      for (int s = 0; s < 32; ++s) acc += nfl[nl][s]*M[s][i];
      kvt[(size_t)n*32 + i] = acc;
    }
  }
  if (t < 64){
    int n = n0 + t;
    if (n < N){
      float acc = bqbk_s;
      #pragma unroll 8
      for (int s = 0; s < 32; ++s) acc += nfl[t][s]*mb[s];
      carr[n] = acc;
    }
  }
}

__global__ void __launch_bounds__(1024) k_scan(const int* __restrict__ cnt,
    int* __restrict__ cursor, float* __restrict__ bnacc, int N, int E){
  __shared__ int part[1024];
  int t = threadIdx.x;
  if (t < 80) bnacc[t] = 0.f;
  int chunk = (N + 1023) >> 10;
  int lo = t*chunk, hi = min(lo+chunk, N);
  int s = 0;
  for (int i = lo; i < hi; ++i) s += cnt[i];
  part[t] = s;
  __syncthreads();
  for (int off = 1; off < 1024; off <<= 1){
    int v = (t >= off) ? part[t-off] : 0;
    __syncthreads();
    part[t] += v;
    __syncthreads();
  }
  int base = (t == 0) ? 0 : part[t-1];
  for (int i = lo; i < hi; ++i){
    cursor[i] = base;
    base += cnt[i];
  }
}

// Per-edge precompute: u = silu(radial@W1+b1) (bf16, MFMA-A tiled layout),
// coefficient tables cAB/cV (bf16, tile-transposed), CSR perm. 64 edges/block.
__global__ void __launch_bounds__(256) k_prep(
    const float* __restrict__ nf, const int* __restrict__ ei,
    const float* __restrict__ sh, const float* __restrict__ radial,
    const float* __restrict__ W1, const float* __restrict__ b1,
    int* __restrict__ cursor,
    __bf16* __restrict__ uG, __bf16* __restrict__ cabG, __bf16* __restrict__ cvG,
    int* __restrict__ permG, int E, int NT)
{
  __shared__ float featT[80][65];
  __shared__ float radl[64][17];
  __shared__ float shlT[4][64];
  __shared__ float w1l[1024];
  __shared__ float b1l[64];
  __shared__ __align__(16) __bf16 u_l[64][72];
  __shared__ __align__(16) __bf16 cab_l[48][64];
  __shared__ __align__(16) __bf16 cv_l[64][3][64];
  __shared__ int src_l[64];

  const int t = threadIdx.x;
  const int e0 = blockIdx.x*64;
  const int tg0 = blockIdx.x*4;

  if (t < 64){
    int ee = e0 + t;
    if (ee < E){
      src_l[t] = ei[ee];
      permG[ee] = atomicAdd(&cursor[ei[(size_t)E+ee]], 1);
    } else src_l[t] = ei[E-1];
    b1l[t] = b1[t];
  }
  {
    int e = t >> 2, c = t & 3;
    int ec = min(e0+e, E-1);
    shlT[c][e] = ntld_f(&sh[(size_t)ec*4+c]);
  }
  for (int i = t; i < 1024; i += 256){
    int e = i >> 4, r = i & 15;
    int ec = min(e0+e, E-1);
    radl[e][r] = ntld_f(&radial[(size_t)ec*16+r]);
  }
  *(float4*)&w1l[t*4] = ((const float4*)W1)[t];
  __syncthreads();

  for (int i = t; i < 5120; i += 256){
    int e = i / 80, idx = i - e*80;
    featT[idx][e] = nf[(size_t)src_l[e]*80 + idx];
  }
  for (int i = t; i < 4096; i += 256){
    int e = i & 63, h = i >> 6;
    float acc = b1l[h];
    #pragma unroll
    for (int r = 0; r < 16; ++r) acc += radl[e][r]*w1l[r*64+h];
    u_l[e][h] = (__bf16)silu_f(acc);
  }
  __syncthreads();

  const float inv_s3 = 0.57735026918962576f;
  const float inv_s2 = 0.70710678118654752f;
  const float a0 = 0.14433756729740643f;  // 1/sqrt(48)
  const float a1 = 0.125f;                // 1/sqrt(64)

  for (int i = t; i < 3072; i += 256){
    int r = i >> 6, e = i & 63;
    float val;
    if (r < 32) val = a0 * shlT[0][e] * featT[r][e];
    else {
      int v = r - 32;
      float dot = (featT[32+v*3][e]*shlT[1][e] + featT[33+v*3][e]*shlT[2][e]
                 + featT[34+v*3][e]*shlT[3][e]) * inv_s3;
      val = a0 * dot;
    }
    cab_l[r][e] = (__bf16)val;
  }
  for (int i = t; i < 12288; i += 256){
    int e = i & 63, r = (i >> 6) & 63, c = i >> 12;
    float val;
    if (r < 32) val = a1 * shlT[1+c][e] * featT[r][e];
    else if (r < 48){
      int v = r - 32;
      val = a1 * shlT[0][e] * featT[32+v*3+c][e];
    } else {
      int v = r - 48;
      int c1 = c+1; if (c1 > 2) c1 -= 3;
      int c2 = c+2; if (c2 > 2) c2 -= 3;
      val = a1 * inv_s2 * (featT[32+v*3+c1][e]*shlT[1+c2][e]
                         - featT[32+v*3+c2][e]*shlT[1+c1][e]);
    }
    cv_l[r][c][e] = (__bf16)val;
  }
  __syncthreads();

  // ---- tiled outputs (16 edges per tile; tile layouts match k_edge lanes)
  // uG[tile]: [k8][e][j8] bf16 (2048 B)
  for (int i = t; i < 512; i += 256){
    int tl = i >> 7, rem = i & 127, k8 = rem >> 4, e = rem & 15;
    if (tg0 + tl < NT){
      bf16x8 v = *(const bf16x8*)&u_l[tl*16 + e][k8*8];
      *(bf16x8*)((char*)uG + (size_t)(tg0+tl)*2048 + k8*256 + e*16) = v;
    }
  }
  // cabG[tile]: [r48][e16] bf16 (1536 B)
  for (int i = t; i < 384; i += 256){
    int tl = i / 96, rem = i - tl*96, r = rem >> 1, h = rem & 1;
    if (tg0 + tl < NT){
      bf16x8 v = *(const bf16x8*)&cab_l[r][tl*16 + h*8];
      *(bf16x8*)((char*)cabG + (size_t)(tg0+tl)*1536 + r*32 + h*16) = v;
    }
  }
  // cvG[tile]: [r64][c3][e16] bf16 (6144 B)
  for (int i = t; i < 1536; i += 256){
    int tl = i / 384, rem = i - tl*384, r = rem / 6, rem2 = rem - r*6,
        c = rem2 >> 1, h = rem2 & 1;
    if (tg0 + tl < NT){
      bf16x8 v = *(const bf16x8*)&cv_l[r][c][tl*16 + h*8];
      *(bf16x8*)((char*)cvG + (size_t)(tg0+tl)*6144 + r*96 + c*32 + h*16) = v;
    }
  }
}

// Panel stored quad-major: conflict-free ds_read_b128 (R8-verified)
#define LOAD_PANEL(BASE_IT, NITS) do {                                         \
    for (int idx = t; idx < (NITS)*128; idx += 1024){                          \
      int itl_ = idx >> 7, rem_ = idx & 127, half_ = rem_ >> 6, r6_ = rem_ & 63;\
      int col_ = r6_ >> 2, quad_ = r6_ & 3;                                    \
      *(float4*)(panel + itl_*2048 + half_*1024 + quad_*256 + col_*16) =       \
        *(const float4*)(w2b + half_*163840 + (size_t)((BASE_IT)+itl_)*1024    \
                         + col_*64 + quad_*16);                                \
    }                                                                          \
    for (int i = t; i < (NITS)*16; i += 1024) b2l[i] = b2[(BASE_IT)*16 + i];   \
  } while(0)

// stage both tiles' cab interleaved: myCab[r*64 + q*16] = [A 8B | B 8B]
#define CAB_STAGE2() do {                                                      \
    for (int i = lane; i < 384; i += 64){                                      \
      int tb_ = i & 1; int c_ = i >> 1;                                        \
      int r_ = c_ >> 2, q_ = c_ & 3;                                           \
      const char* s_ = cabGb + (size_t)(tb_ ? cB : cA)*1536 + r_*32 + q_*8;    \
      unsigned long long v_ = *(const unsigned long long*)s_;                  \
      *(unsigned long long*)(myCab + r_*64 + q_*16 + tb_*8) = v_;              \
    }                                                                          \
  } while(0)

// stage 16 cv rows of (HALF,SUB) packed: q01A@0, q01B@1024, q2AB@2048
#define CV_STAGE2(SUB, HALF) do {                                              \
    for (int i = lane; i < 384; i += 64){                                      \
      int tb_ = i & 1; int x_ = i >> 1;                                        \
      int c3_ = x_ % 3; int rem_ = x_ / 3;                                     \
      int il_ = rem_ >> 2, q_ = rem_ & 3;                                      \
      const char* s_ = cvGb + (size_t)(tb_ ? cB : cA)*6144 + (HALF)*3072       \
                     + ((SUB)*16 + il_)*96 + c3_*32 + q_*8;                    \
      unsigned long long v_ = *(const unsigned long long*)s_;                  \
      char* d_ = (c3_ < 2) ? (myCab + tb_*1024 + il_*64 + q_*16 + c3_*8)       \
                           : (myCab + 2048 + il_*64 + q_*16 + tb_*8);          \
      *(unsigned long long*)d_ = v_;                                           \
    }                                                                          \
  } while(0)

// One S pair-loop over the resident 48-it panel; single b128 coef read
// covers both tiles; bias from b2l (in-loop, R11 semantics).
#define S_PAIR(SECOND, TA, TB) do {                                            \
    _Pragma("unroll 4")                                                        \
    for (int itl = 0; itl < 48; ++itl){                                        \
      bf16x8 B0_ = *(const bf16x8*)(panel + itl*2048 + laneOff);               \
      bf16x8 B1_ = *(const bf16x8*)(panel + itl*2048 + 1024 + laneOff);        \
      f32x4 dA_; dA_[0]=0;dA_[1]=0;dA_[2]=0;dA_[3]=0; f32x4 dB_ = dA_;         \
      dA_ = __builtin_amdgcn_mfma_f32_16x16x32_bf16(u##TA##_0, B0_, dA_, 0,0,0);\
      dB_ = __builtin_amdgcn_mfma_f32_16x16x32_bf16(u##TB##_0, B0_, dB_, 0,0,0);\
      dA_ = __builtin_amdgcn_mfma_f32_16x16x32_bf16(u##TA##_1, B1_, dA_, 0,0,0);\
      dB_ = __builtin_amdgcn_mfma_f32_16x16x32_bf16(u##TB##_1, B1_, dB_, 0,0,0);\
      const float bias_ = b2l[itl*16 + nlo];                                   \
      f32x2 bb_; bb_[0]=bias_; bb_[1]=bias_;                                   \
      f32x2 dAlo_ = __builtin_shufflevector(dA_,dA_,0,1) + bb_;                \
      f32x2 dAhi_ = __builtin_shufflevector(dA_,dA_,2,3) + bb_;                \
      f32x2 dBlo_ = __builtin_shufflevector(dB_,dB_,0,1) + bb_;                \
      f32x2 dBhi_ = __builtin_shufflevector(dB_,dB_,2,3) + bb_;                \
      const int r_ = (SECOND)*24 + (itl>>1);                                   \
      bf16x8 c8_ = *(const bf16x8*)(myCab + r_*64 + quad*16);                  \
      bf16x4 cA_ = __builtin_shufflevector(c8_, c8_, 0,1,2,3);                 \
      bf16x4 cB_ = __builtin_shufflevector(c8_, c8_, 4,5,6,7);                 \
      if (itl & 1){                                                            \
        s1l##TA += b4lo(cA_)*dAlo_; s1h##TA += b4hi(cA_)*dAhi_;                \
        s1l##TB += b4lo(cB_)*dBlo_; s1h##TB += b4hi(cB_)*dBhi_;                \
      } else {                                                                 \
        s0l##TA += b4lo(cA_)*dAlo_; s0h##TA += b4hi(cA_)*dAhi_;                \
        s0l##TB += b4lo(cB_)*dBlo_; s0h##TB += b4hi(cB_)*dBhi_;                \
      }                                                                        \
    }                                                                          \
  } while(0)

// One V pair-sub-loop: 16 panel its; coef reads = 3 b128 (both tiles);
// bias from b2l (in-loop).
#define V_PAIR_SUB(SUB, TA, TB) do {                                           \
    _Pragma("unroll 4")                                                        \
    for (int il = 0; il < 16; ++il){                                           \
      const int gitl = (SUB)*16 + il;                                          \
      bf16x8 B0_ = *(const bf16x8*)(panel + gitl*2048 + laneOff);              \
      bf16x8 B1_ = *(const bf16x8*)(panel + gitl*2048 + 1024 + laneOff);       \
      f32x4 dA_; dA_[0]=0;dA_[1]=0;dA_[2]=0;dA_[3]=0; f32x4 dB_ = dA_;         \
      dA_ = __builtin_amdgcn_mfma_f32_16x16x32_bf16(u##TA##_0, B0_, dA_, 0,0,0);\
      dB_ = __builtin_amdgcn_mfma_f32_16x16x32_bf16(u##TB##_0, B0_, dB_, 0,0,0);\
      dA_ = __builtin_amdgcn_mfma_f32_16x16x32_bf16(u##TA##_1, B1_, dA_, 0,0,0);\
      dB_ = __builtin_amdgcn_mfma_f32_16x16x32_bf16(u##TB##_1, B1_, dB_, 0,0,0);\
      const float bias_ = b2l[gitl*16 + nlo];                                  \
      f32x2 bb_; bb_[0]=bias_; bb_[1]=bias_;                                   \
      f32x2 dAlo_ = __builtin_shufflevector(dA_,dA_,0,1) + bb_;                \
      f32x2 dAhi_ = __builtin_shufflevector(dA_,dA_,2,3) + bb_;                \
      f32x2 dBlo_ = __builtin_shufflevector(dB_,dB_,0,1) + bb_;                \
      f32x2 dBhi_ = __builtin_shufflevector(dB_,dB_,2,3) + bb_;                \
      bf16x8 cA01_ = *(const bf16x8*)(myCab + il*64 + quad*16);                \
      bf16x8 cB01_ = *(const bf16x8*)(myCab + 1024 + il*64 + quad*16);         \
      bf16x8 c2_   = *(const bf16x8*)(myCab + 2048 + il*64 + quad*16);         \
      bf16x4 q0A_ = __builtin_shufflevector(cA01_, cA01_, 0,1,2,3);            \
      bf16x4 q1A_ = __builtin_shufflevector(cA01_, cA01_, 4,5,6,7);            \
      bf16x4 q0B_ = __builtin_shufflevector(cB01_, cB01_, 0,1,2,3);            \
      bf16x4 q1B_ = __builtin_shufflevector(cB01_, cB01_, 4,5,6,7);            \
      bf16x4 q2A_ = __builtin_shufflevector(c2_, c2_, 0,1,2,3);                \
      bf16x4 q2B_ = __builtin_shufflevector(c2_, c2_, 4,5,6,7);                \
      v0l##TA += b4lo(q0A_)*dAlo_; v0h##TA += b4hi(q0A_)*dAhi_;                \
      v1l##TA += b4lo(q1A_)*dAlo_; v1h##TA += b4hi(q1A_)*dAhi_;                \
      v2l##TA += b4lo(q2A_)*dAlo_; v2h##TA += b4hi(q2A_)*dAhi_;                \
      v0l##TB += b4lo(q0B_)*dBlo_; v0h##TB += b4hi(q0B_)*dBhi_;                \
      v1l##TB += b4lo(q1B_)*dBlo_; v1h##TB += b4hi(q1B_)*dBhi_;                \
      v2l##TB += b4lo(q2B_)*dBlo_; v2h##TB += b4hi(q2B_)*dBhi_;                \
    }                                                                          \
  } while(0)

#define S_FLUSH(TG, S0LO, S0HI, S1LO, S1HI) do {                               \
      myOut[(eb+0)*56 + nlo] = S0LO[0];                                        \
      myOut[(eb+1)*56 + nlo] = S0LO[1];                                        \
      myOut[(eb+2)*56 + nlo] = S0HI[0];                                        \
      myOut[(eb+3)*56 + nlo] = S0HI[1];                                        \
      myOut[(eb+0)*56 + 16+nlo] = S1LO[0];                                     \
      myOut[(eb+1)*56 + 16+nlo] = S1LO[1];                                     \
      myOut[(eb+2)*56 + 16+nlo] = S1HI[0];                                     \
      myOut[(eb+3)*56 + 16+nlo] = S1HI[1];                                     \
      const int e0e = (TG)*16;                                                 \
      { int e = lane>>2, seg = lane&3, eg = e0e + e;                           \
        if (eg < E){                                                           \
          f32x4 m0 = *(const f32x4*)&myOut[e*56 + seg*8];                      \
          f32x4 m1 = *(const f32x4*)&myOut[e*56 + seg*8 + 4];                  \
          bf16x8 o; o[0]=(__bf16)m0[0]; o[1]=(__bf16)m0[1];                    \
          o[2]=(__bf16)m0[2]; o[3]=(__bf16)m0[3]; o[4]=(__bf16)m1[0];          \
          o[5]=(__bf16)m1[1]; o[6]=(__bf16)m1[2]; o[7]=(__bf16)m1[3];          \
          nt_store_b8(msgs + (size_t)permG[eg]*80 + seg*8, o);                 \
        } }                                                                    \
      for (int r8 = 0; r8 < 2; ++r8){                                          \
        int e = r8*8 + (lane>>3), kq = lane&7, eg = e0e + e;                   \
        f32x4 ms = *(const f32x4*)&myOut[e*56 + kq*4];                         \
        int dn = ei[(size_t)E + min(eg, E-1)];                                 \
        const float* kvp = kvt + (size_t)dn*32 + kq*4;                         \
        float part = ms[0]*kvp[0]+ms[1]*kvp[1]+ms[2]*kvp[2]+ms[3]*kvp[3];      \
        part += __shfl_xor(part, 1);                                           \
        part += __shfl_xor(part, 2);                                           \
        part += __shfl_xor(part, 4);                                           \
        if (kq == 0 && eg < E){                                                \
          float lg = (part + carr[dn]) * 0.35355339059327373f                  \
                   + logf(ntld_f(&env[eg]) + 1e-8f);                           \
          nt_store_f(&logits_s[permG[eg]], lg);                                \
        } }                                                                    \
  } while(0)

#define V_FLUSH(TG, V0LO, V0HI, V1LO, V1HI, V2LO, V2HI) do {                   \
      const int cb2 = nlo*3;                                                   \
      myOut[(eb+0)*56 + cb2+0] = V0LO[0];                                      \
      myOut[(eb+1)*56 + cb2+0] = V0LO[1];                                      \
      myOut[(eb+2)*56 + cb2+0] = V0HI[0];                                      \
      myOut[(eb+3)*56 + cb2+0] = V0HI[1];                                      \
      myOut[(eb+0)*56 + cb2+1] = V1LO[0];                                      \
      myOut[(eb+1)*56 + cb2+1] = V1LO[1];                                      \
      myOut[(eb+2)*56 + cb2+1] = V1HI[0];                                      \
      myOut[(eb+3)*56 + cb2+1] = V1HI[1];                                      \
      myOut[(eb+0)*56 + cb2+2] = V2LO[0];                                      \
      myOut[(eb+1)*56 + cb2+2] = V2LO[1];                                      \
      myOut[(eb+2)*56 + cb2+2] = V2HI[0];                                      \
      myOut[(eb+3)*56 + cb2+2] = V2HI[1];                                      \
      const int e0e = (TG)*16;                                                 \
      for (int i = lane; i < 96; i += 64){                                     \
        int e = i/6, seg = i - (i/6)*6, eg = e0e + e;                          \
        if (eg < E){                                                           \
          f32x4 m0 = *(const f32x4*)&myOut[e*56 + seg*8];                      \
          f32x4 m1 = *(const f32x4*)&myOut[e*56 + seg*8 + 4];                  \
          bf16x8 o; o[0]=(__bf16)m0[0]; o[1]=(__bf16)m0[1];                    \
          o[2]=(__bf16)m0[2]; o[3]=(__bf16)m0[3]; o[4]=(__bf16)m1[0];          \
          o[5]=(__bf16)m1[1]; o[6]=(__bf16)m1[2]; o[7]=(__bf16)m1[3];          \
          nt_store_b8(msgs + (size_t)permG[eg]*80 + 32 + seg*8, o);            \
        } }                                                                    \
  } while(0)

// Persistent-panel edge kernel: 256 blocks x 1024 threads (4 waves/SIMD).
// Packed coef staging: inner-loop coef reads are b128 covering BOTH tiles
// (S: 1 read vs 2, V: 3 reads vs 6). Bias stays in-loop (R12's precompute
// regressed k_prep 4x its savings). LDS = 96K panel + 56K wstage + 3K b2l.
__global__ void __launch_bounds__(1024, 4) k_edge(
    const __bf16* __restrict__ W2t, const float* __restrict__ b2,
    const __bf16* __restrict__ uG, const __bf16* __restrict__ cabG,
    const __bf16* __restrict__ cvG, const int* __restrict__ ei,
    const int* __restrict__ permG, const float* __restrict__ kvt,
    const float* __restrict__ carr, const float* __restrict__ env,
    __bf16* __restrict__ msgs, float* __restrict__ logits_s, int E, int NT)
{
  __shared__ __align__(16) char panel[98304];      // 48 its x 2048 B (swizzled)
  __shared__ __align__(16) char wstage[16][3584];  // per wave: coef stage / out alias
  __shared__ float b2l[768];

  const int t = threadIdx.x;
  const int lane = t & 63;
  const int wv   = t >> 6;
  const int quad = lane >> 4;
  const int nlo  = lane & 15;
  const int wgid = blockIdx.x*16 + wv;
  const int laneOff = quad*256 + nlo*16;
  const int uOff    = quad*256 + nlo*16;
  char*  myCab = wstage[wv];
  float* myOut = (float*)wstage[wv];      // aliases coef stage (flush after loops only)
  const char* w2b   = (const char*)W2t;
  const char* uGb   = (const char*)uG;
  const char* cabGb = (const char*)cabG;
  const char* cvGb  = (const char*)cvG;

  const int tA = wgid, tB = wgid + 4096;
  const bool hA = tA < NT, hB = tB < NT;
  const int cA = min(tA, NT-1), cB = min(tB, NT-1);

  // ---- hoisted u fragments (used in all 4 phases)
  const bf16x8 uA_0 = *(const bf16x8*)(uGb + (size_t)cA*2048 + uOff);
  const bf16x8 uA_1 = *(const bf16x8*)(uGb + (size_t)cA*2048 + 1024 + uOff);
  const bf16x8 uB_0 = *(const bf16x8*)(uGb + (size_t)cB*2048 + uOff);
  const bf16x8 uB_1 = *(const bf16x8*)(uGb + (size_t)cB*2048 + 1024 + uOff);

  // ---- S partials (registers, live S0->S1)
  f32x2 s0lA={0,0}, s0hA={0,0}, s1lA={0,0}, s1hA={0,0};
  f32x2 s0lB={0,0}, s0hB={0,0}, s1lB={0,0}, s1hB={0,0};

  const int eb = quad*4;

  // ---- S phases: cab staged ONCE (packed, both tiles), reused in S1
  LOAD_PANEL(0, 48);
  CAB_STAGE2();
  __syncthreads();
  S_PAIR(0, A, B);
  __syncthreads();
  LOAD_PANEL(48, 48);
  __syncthreads();
  S_PAIR(1, A, B);
  if (hA) S_FLUSH(tA, s0lA, s0hA, s1lA, s1hA);
  if (hB) S_FLUSH(tB, s0lB, s0hB, s1lB, s1hB);
  __syncthreads();

  // ---- V partials (registers, live V0->V1)
  f32x2 v0lA={0,0}, v0hA={0,0}, v1lA={0,0}, v1hA={0,0}, v2lA={0,0}, v2hA={0,0};
  f32x2 v0lB={0,0}, v0hB={0,0}, v1lB={0,0}, v1hB={0,0}, v2lB={0,0}, v2hB={0,0};

  LOAD_PANEL(96, 32);
  __syncthreads();
  CV_STAGE2(0, 0);
  V_PAIR_SUB(0, A, B);
  CV_STAGE2(1, 0);
  V_PAIR_SUB(1, A, B);
  __syncthreads();
  LOAD_PANEL(128, 32);
  __syncthreads();
  CV_STAGE2(0, 1);
  V_PAIR_SUB(0, A, B);
  CV_STAGE2(1, 1);
  V_PAIR_SUB(1, A, B);
  if (hA) V_FLUSH(tA, v0lA, v0hA, v1lA, v1hA, v2lA, v2hA);
  if (hB) V_FLUSH(tB, v0lB, v0hB, v1lB, v1hB, v2lB, v2hB);
}

// One wave per node: max pass, merged gather+den pass (bf16 msgs, NT loads),
// fused node matmuls + gate + residual + BN stats.
__global__ void __launch_bounds__(256) k_agg(
    const __bf16* __restrict__ msgs, const float* __restrict__ logits_s,
    const int* __restrict__ cursor, const float* __restrict__ nf,
    const float* __restrict__ Wout_s, const float* __restrict__ Wout_v,
    const float* __restrict__ Wg_s, const float* __restrict__ Wg_v,
    float* __restrict__ xbuf, float* __restrict__ bnacc, int N)
{
  __shared__ float aggl[4][80];
  __shared__ float t1[4][96];
  __shared__ float t2[4][96];
  __shared__ float bnl[80];
  const int t = threadIdx.x, l = t & 63, wv = t >> 6;
  const int n = blockIdx.x*4 + wv;
  const bool act = (n < N);
  const int nc = act ? n : (N-1);
  if (t < 80) bnl[t] = 0.f;

  const int r0 = (nc == 0) ? 0 : cursor[nc-1];
  const int r1 = cursor[nc];
  const int deg = act ? (r1 - r0) : 0;

  float mym = -3.4e38f;
  for (int i = l; i < deg; i += 64) mym = fmaxf(mym, logits_s[r0+i]);
  #pragma unroll
  for (int s = 32; s; s >>= 1) mym = fmaxf(mym, __shfl_xor(mym, s));
  float denp = 0.f, acc0 = 0.f, acc1 = 0.f;
  for (int c0 = 0; c0 < deg; c0 += 64){
    const int len = min(64, deg - c0);
    float ex = 0.f;
    if (l < len) ex = __expf(logits_s[r0+c0+l] - mym);
    denp += ex;
    for (int j0 = 0; j0 < len; j0 += 4){
      const int jn = len - j0;
      const __bf16* base = msgs + (size_t)(r0+c0+j0)*80;
      float v0=0,v1=0,v2=0,v3=0, w0=0,w1=0,w2=0,w3=0;
      float a0_=0,a1_=0,a2_=0,a3_=0;
      v0 = ntbf(&base[l]); if (l < 16) w0 = ntbf(&base[64+l]); a0_ = __shfl(ex, j0);
      if (jn > 1){ v1 = ntbf(&base[80+l]);  if (l < 16) w1 = ntbf(&base[144+l]); a1_ = __shfl(ex, j0+1); }
      if (jn > 2){ v2 = ntbf(&base[160+l]); if (l < 16) w2 = ntbf(&base[224+l]); a2_ = __shfl(ex, j0+2); }
      if (jn > 3){ v3 = ntbf(&base[240+l]); if (l < 16) w3 = ntbf(&base[304+l]); a3_ = __shfl(ex, j0+3); }
      acc0 += a0_*v0 + a1_*v1 + a2_*v2 + a3_*v3;
      if (l < 16) acc1 += a0_*w0 + a1_*w1 + a2_*w2 + a3_*w3;
    }
  }
  #pragma unroll
  for (int s = 32; s; s >>= 1) denp += __shfl_xor(denp, s);
  const float inv = 1.f/(denp + 1e-8f);
  aggl[wv][l] = acc0 * inv;
  if (l < 16) aggl[wv][64+l] = acc1 * inv;
  __syncthreads();

  const float* arow = &aggl[wv][0];
  const float iS = 0.17677669529663687f;  // 1/sqrt(32)
  const float iV = 0.25f;                 // 1/sqrt(16)
  for (int o = l; o < 80; o += 64){
    float val = 0.f;
    if (o < 32){
      for (int s = 0; s < 32; ++s) val += arow[s]*Wout_s[s*32+o];
      val *= iS;
    } else {
      int w = (o-32)/3, c = (o-32)-w*3;
      for (int v = 0; v < 16; ++v) val += arow[32+v*3+c]*Wout_v[v*16+w];
      val *= iV;
    }
    t1[wv][o] = val;
  }
  __syncthreads();
  for (int o = l; o < 96; o += 64){
    float val = 0.f;
    if (o < 48){
      for (int k = 0; k < 32; ++k) val += t1[wv][k]*Wg_s[k*48+o];
      val *= iS;
    } else {
      int w = (o-48)/3, c = (o-48)-w*3;
      for (int v = 0; v < 16; ++v) val += t1[wv][32+v*3+c]*Wg_v[v*16+w];
      val *= iV;
    }
    t2[wv][o] = val;
  }
  __syncthreads();
  for (int o = l; o < 80; o += 64){
    float x;
    if (o < 32){
      x = silu_f(t2[wv][o]) + nf[(size_t)nc*80+o];
      if (act){
        nt_store_f(&xbuf[(size_t)n*80+o], x);
        atomicAdd(&bnl[o], x);
        atomicAdd(&bnl[32+o], x*x);
      }
    } else {
      int w = (o-32)/3;
      x = sigm_f(t2[wv][32+w]) * t2[wv][48+(o-32)] + nf[(size_t)nc*80+o];
      if (act){
        nt_store_f(&xbuf[(size_t)n*80+o], x);
        atomicAdd(&bnl[64+w], x*x);
      }
    }
  }
  __syncthreads();
  if (t < 80) atomicAdd(&bnacc[t], bnl[t]);
}

__global__ void __launch_bounds__(256) k_out(const float* __restrict__ xbuf,
    const float* __restrict__ bnacc,
    const float* __restrict__ bn_ws, const float* __restrict__ bn_bs,
    const float* __restrict__ bn_wv, float* __restrict__ out, int N){
  __shared__ float coef[80];
  int t = threadIdx.x;
  float fN = (float)N;
  if (t < 32){
    float mean = bnacc[t]/fN;
    float var = bnacc[32+t]/fN - mean*mean;
    float cm = bn_ws[t]*rsqrtf(var + 1e-5f);
    coef[t] = cm;
    coef[32+t] = bn_bs[t] - mean*cm;
  } else if (t < 48){
    int v = t - 32;
    coef[64+v] = bn_wv[v]*rsqrtf(bnacc[64+v]/(3.f*fN) + 1e-5f);
  }
  __syncthreads();
  int i = blockIdx.x*256 + t;
  if (i >= N*80) return;
  int o = i - (i/80)*80;
  float x = ntld_f(&xbuf[i]);
  nt_store_f(&out[i], (o < 32) ? (x*coef[o] + coef[32+o]) : (x*coef[64+(o-32)/3]));
}

extern "C" void kernel_launch(void* const* d_in, const int* in_sizes, int n_in,
                              void* d_out, int out_size, void* d_ws, size_t ws_size,
                              hipStream_t stream) {
  const float* nf     = (const float*)d_in[0];
  const int*   ei     = (const int*)  d_in[1];
  const float* sh     = (const float*)d_in[2];
  const float* radial = (const float*)d_in[3];
  const float* env    = (const float*)d_in[4];
  const float* W1     = (const float*)d_in[5];
  const float* b1     = (const float*)d_in[6];
  const float* W2     = (const float*)d_in[7];
  const float* b2     = (const float*)d_in[8];
  const float* Wq     = (const float*)d_in[9];
  const float* bq     = (const float*)d_in[10];
  const float* Wk     = (const float*)d_in[11];
  const float* bk     = (const float*)d_in[12];
  const float* Wout_s = (const float*)d_in[13];
  const float* Wout_v = (const float*)d_in[14];
  const float* Wg_s   = (const float*)d_in[15];
  const float* Wg_v   = (const float*)d_in[16];
  const float* bn_ws  = (const float*)d_in[17];
  const float* bn_bs  = (const float*)d_in[18];
  const float* bn_wv  = (const float*)d_in[19];

  const int E = in_sizes[4];
  const int N = in_sizes[0] / 80;
  const int NT = (E + 15)/16;

  float* ws = (float*)d_ws;
  size_t off = 0;
  __bf16* w2t    = (__bf16*)(ws + off); off += 81920;          // 320 KB bf16
  __bf16* msgs   = (__bf16*)(ws + off); off += (size_t)E*40;   // E*80 bf16
  float* logits_s= ws + off; off += E;
  int* cnt       = (int*)(ws + off); off += N;
  int* cursor    = (int*)(ws + off); off += N;
  float* xbuf    = ws + off; off += (size_t)N*80;
  float* bnacc   = ws + off; off += 80;
  float* kvt     = ws + off; off += (size_t)N*32;
  float* carr    = ws + off; off += N;
  int* permG     = (int*)(ws + off); off += E;
  __bf16* uG     = (__bf16*)(ws + off); off += (size_t)NT*512;   // NT*2048 B
  __bf16* cabG   = (__bf16*)(ws + off); off += (size_t)NT*384;   // NT*1536 B
  __bf16* cvG    = (__bf16*)(ws + off); off += (size_t)NT*1536;  // NT*6144 B

  hipMemsetAsync(cnt, 0, (size_t)N*sizeof(int), stream);

  const int nbPrep = 640;                 // 163840/256
  const int nbHist = (E + 255)/256;
  const int nbKv   = (N + 63)/64;
  k_setup<<<nbPrep + nbHist + nbKv, 256, 0, stream>>>(W2, w2t, ei, cnt,
      nf, Wq, bq, Wk, bk, kvt, carr, nbPrep, nbHist, N, E);
  k_scan<<<1, 1024, 0, stream>>>(cnt, cursor, bnacc, N, E);
  k_prep<<<(E + 63)/64, 256, 0, stream>>>(nf, ei, sh, radial, W1, b1, cursor,
      uG, cabG, cvG, permG, E, NT);
  k_edge<<<256, 1024, 0, stream>>>(w2t, b2, uG, cabG, cvG, ei, permG,
      kvt, carr, env, msgs, logits_s, E, NT);
  k_agg<<<(N + 3)/4, 256, 0, stream>>>(msgs, logits_s, cursor, nf,
      Wout_s, Wout_v, Wg_s, Wg_v, xbuf, bnacc, N);
  k_out<<<(N*80 + 255)/256, 256, 0, stream>>>(xbuf, bnacc, bn_ws, bn_bs, bn_wv,
      (float*)d_out, N);
}

// Round 14
// 314.589 us; speedup vs baseline: 1.3926x; 1.1389x over previous
//
#include <hip/hip_runtime.h>
#include <math.h>

typedef __bf16 bf16x8 __attribute__((ext_vector_type(8)));
typedef __bf16 bf16x4 __attribute__((ext_vector_type(4)));
typedef float  f32x4  __attribute__((ext_vector_type(4)));
typedef float  f32x2  __attribute__((ext_vector_type(2)));
typedef unsigned long long u64x2 __attribute__((ext_vector_type(2)));

__device__ __forceinline__ float silu_f(float x){ return x / (1.f + __expf(-x)); }
__device__ __forceinline__ float sigm_f(float x){ return 1.f / (1.f + __expf(-x)); }

__device__ __forceinline__ float ntld_f(const float* p){
  return __builtin_nontemporal_load(p);
}
__device__ __forceinline__ float ntbf(const __bf16* p){
  unsigned short us = __builtin_nontemporal_load((const unsigned short*)p);
  union { unsigned u; float f; } cv; cv.u = ((unsigned)us) << 16;
  return cv.f;
}
__device__ __forceinline__ void nt_store_f(float* p, float v){
  __builtin_nontemporal_store(v, p);
}
__device__ __forceinline__ void nt_store_b8(__bf16* p, bf16x8 v){
  u64x2 u; __builtin_memcpy(&u, &v, 16);
  __builtin_nontemporal_store(u, (u64x2*)p);
}
__device__ __forceinline__ f32x2 b4lo(bf16x4 v){ f32x2 r; r[0]=(float)v[0]; r[1]=(float)v[1]; return r; }
__device__ __forceinline__ f32x2 b4hi(bf16x4 v){ f32x2 r; r[0]=(float)v[2]; r[1]=(float)v[3]; return r; }

// Block ranges: [0,nbPrep) W2->bf16 transpose; [nbPrep,+nbHist) dst histogram;
// rest: per-node attention vectors kv[n]=Wk@(nf@Wq+bq), c[n]=(nf@Wq+bq).bk
__global__ void __launch_bounds__(256) k_setup(const float* __restrict__ W2,
    __bf16* __restrict__ W2t, const int* __restrict__ ei, int* __restrict__ cnt,
    const float* __restrict__ nf, const float* __restrict__ Wq,
    const float* __restrict__ bq, const float* __restrict__ Wk,
    const float* __restrict__ bk, float* __restrict__ kvt, float* __restrict__ carr,
    int nbPrep, int nbHist, int N, int E){
  int b = blockIdx.x, t = threadIdx.x;
  if (b < nbPrep){
    int gid = b*256 + t;   // 163840 total
    int h = gid / 2560;
    int col = gid - h*2560;
    W2t[(size_t)(h>>5)*81920 + col*32 + (h&31)] = (__bf16)ntld_f(&W2[gid]);
    return;
  }
  if (b < nbPrep + nbHist){
    int e = (b - nbPrep)*256 + t;
    if (e < E) atomicAdd(&cnt[ei[E+e]], 1);
    return;
  }
  __shared__ float M[32][33];
  __shared__ float mb[32];
  __shared__ float nfl[64][33];
  __shared__ float bqbk_s;
  const int n0 = (b - nbPrep - nbHist)*64;
  for (int idx = t; idx < 1024; idx += 256){
    int s = idx >> 5, i = idx & 31;
    float acc = 0.f;
    #pragma unroll
    for (int j = 0; j < 8; ++j) acc += Wq[s*8+j]*Wk[i*8+j];
    M[s][i] = acc;
  }
  if (t < 32){
    float acc = 0.f;
    #pragma unroll
    for (int j = 0; j < 8; ++j) acc += Wq[t*8+j]*bk[j];
    mb[t] = acc;
  }
  if (t == 0){
    float acc = 0.f;
    #pragma unroll
    for (int j = 0; j < 8; ++j) acc += bq[j]*bk[j];
    bqbk_s = acc;
  }
  for (int idx = t; idx < 2048; idx += 256){
    int nl = idx >> 5, s = idx & 31;
    int n = n0 + nl;
    nfl[nl][s] = (n < N) ? nf[(size_t)n*80 + s] : 0.f;
  }
  __syncthreads();
  for (int idx = t; idx < 2048; idx += 256){
    int nl = idx >> 5, i = idx & 31;
    int n = n0 + nl;
    if (n < N){
      float acc = 0.f;
      #pragma unroll 8
      for (int s = 0; s < 32; ++s) acc += nfl[nl][s]*M[s][i];
      kvt[(size_t)n*32 + i] = acc;
    }
  }
  if (t < 64){
    int n = n0 + t;
    if (n < N){
      float acc = bqbk_s;
      #pragma unroll 8
      for (int s = 0; s < 32; ++s) acc += nfl[t][s]*mb[s];
      carr[n] = acc;
    }
  }
}

__global__ void __launch_bounds__(1024) k_scan(const int* __restrict__ cnt,
    int* __restrict__ cursor, float* __restrict__ bnacc, int N, int E){
  __shared__ int part[1024];
  int t = threadIdx.x;
  if (t < 80) bnacc[t] = 0.f;
  int chunk = (N + 1023) >> 10;
  int lo = t*chunk, hi = min(lo+chunk, N);
  int s = 0;
  for (int i = lo; i < hi; ++i) s += cnt[i];
  part[t] = s;
  __syncthreads();
  for (int off = 1; off < 1024; off <<= 1){
    int v = (t >= off) ? part[t-off] : 0;
    __syncthreads();
    part[t] += v;
    __syncthreads();
  }
  int base = (t == 0) ? 0 : part[t-1];
  for (int i = lo; i < hi; ++i){
    cursor[i] = base;
    base += cnt[i];
  }
}

// Per-edge precompute, LDS diet: coef staging deleted — each thread computes
// 8 consecutive-e values for a fixed (r[,c],half) and writes the bf16x8
// directly into the tiled cabG/cvG layout. LDS 71->40 KB => 4 blocks/CU.
__global__ void __launch_bounds__(256, 4) k_prep(
    const float* __restrict__ nf, const int* __restrict__ ei,
    const float* __restrict__ sh, const float* __restrict__ radial,
    const float* __restrict__ W1, const float* __restrict__ b1,
    int* __restrict__ cursor,
    __bf16* __restrict__ uG, __bf16* __restrict__ cabG, __bf16* __restrict__ cvG,
    int* __restrict__ permG, int E, int NT)
{
  __shared__ float featT[80][65];
  __shared__ float radl[64][17];
  __shared__ float shlT[4][64];
  __shared__ float w1l[1024];
  __shared__ float b1l[64];
  __shared__ __align__(16) __bf16 u_l[64][72];
  __shared__ int src_l[64];

  const int t = threadIdx.x;
  const int e0 = blockIdx.x*64;
  const int tg0 = blockIdx.x*4;

  if (t < 64){
    int ee = e0 + t;
    if (ee < E){
      src_l[t] = ei[ee];
      permG[ee] = atomicAdd(&cursor[ei[(size_t)E+ee]], 1);
    } else src_l[t] = ei[E-1];
    b1l[t] = b1[t];
  }
  {
    int e = t >> 2, c = t & 3;
    int ec = min(e0+e, E-1);
    shlT[c][e] = ntld_f(&sh[(size_t)ec*4+c]);
  }
  for (int i = t; i < 1024; i += 256){
    int e = i >> 4, r = i & 15;
    int ec = min(e0+e, E-1);
    radl[e][r] = ntld_f(&radial[(size_t)ec*16+r]);
  }
  *(float4*)&w1l[t*4] = ((const float4*)W1)[t];
  __syncthreads();

  for (int i = t; i < 5120; i += 256){
    int e = i / 80, idx = i - e*80;
    featT[idx][e] = nf[(size_t)src_l[e]*80 + idx];
  }
  for (int i = t; i < 4096; i += 256){
    int e = i & 63, h = i >> 6;
    float acc = b1l[h];
    #pragma unroll
    for (int r = 0; r < 16; ++r) acc += radl[e][r]*w1l[r*64+h];
    u_l[e][h] = (__bf16)silu_f(acc);
  }
  __syncthreads();

  const float inv_s3 = 0.57735026918962576f;
  const float inv_s2 = 0.70710678118654752f;
  const float a0 = 0.14433756729740643f;  // 1/sqrt(48)
  const float a1 = 0.125f;                // 1/sqrt(64)

  // ---- uG[tile]: [k8][e][j8] bf16 (2048 B)
  for (int i = t; i < 512; i += 256){
    int tl = i >> 7, rem = i & 127, k8 = rem >> 4, e = rem & 15;
    if (tg0 + tl < NT){
      bf16x8 v = *(const bf16x8*)&u_l[tl*16 + e][k8*8];
      *(bf16x8*)((char*)uG + (size_t)(tg0+tl)*2048 + k8*256 + e*16) = v;
    }
  }
  // ---- cab direct: 384 items (h=i&1, tl=(i>>1)&3, r=i>>3) -> bf16x8 each
  for (int i = t; i < 384; i += 256){
    int h = i & 1, tl = (i >> 1) & 3, r = i >> 3;
    if (tg0 + tl >= NT) continue;
    bf16x8 o;
    #pragma unroll
    for (int j = 0; j < 8; ++j){
      int e = tl*16 + h*8 + j;
      float val;
      if (r < 32) val = a0 * shlT[0][e] * featT[r][e];
      else {
        int v = r - 32;
        float dot = (featT[32+v*3][e]*shlT[1][e] + featT[33+v*3][e]*shlT[2][e]
                   + featT[34+v*3][e]*shlT[3][e]) * inv_s3;
        val = a0 * dot;
      }
      o[j] = (__bf16)val;
    }
    *(bf16x8*)((char*)cabG + (size_t)(tg0+tl)*1536 + r*32 + h*16) = o;
  }
  // ---- cv direct: 1536 items (h=i&1, tl=(i>>1)&3, c=(i>>3)%3, r=i/24)
  for (int i = t; i < 1536; i += 256){
    int h = i & 1, tl = (i >> 1) & 3, c = (i >> 3) % 3, r = i / 24;
    if (tg0 + tl >= NT) continue;
    int c1 = c+1; if (c1 > 2) c1 -= 3;
    int c2 = c+2; if (c2 > 2) c2 -= 3;
    bf16x8 o;
    #pragma unroll
    for (int j = 0; j < 8; ++j){
      int e = tl*16 + h*8 + j;
      float val;
      if (r < 32) val = a1 * shlT[1+c][e] * featT[r][e];
      else if (r < 48){
        int v = r - 32;
        val = a1 * shlT[0][e] * featT[32+v*3+c][e];
      } else {
        int v = r - 48;
        val = a1 * inv_s2 * (featT[32+v*3+c1][e]*shlT[1+c2][e]
                           - featT[32+v*3+c2][e]*shlT[1+c1][e]);
      }
      o[j] = (__bf16)val;
    }
    *(bf16x8*)((char*)cvG + (size_t)(tg0+tl)*6144 + r*96 + c*32 + h*16) = o;
  }
}

// Panel stored quad-major: conflict-free ds_read_b128 (R8-verified)
#define LOAD_PANEL(BASE_IT, NITS) do {                                         \
    for (int idx = t; idx < (NITS)*128; idx += 1024){                          \
      int itl_ = idx >> 7, rem_ = idx & 127, half_ = rem_ >> 6, r6_ = rem_ & 63;\
      int col_ = r6_ >> 2, quad_ = r6_ & 3;                                    \
      *(float4*)(panel + itl_*2048 + half_*1024 + quad_*256 + col_*16) =       \
        *(const float4*)(w2b + half_*163840 + (size_t)((BASE_IT)+itl_)*1024    \
                         + col_*64 + quad_*16);                                \
    }                                                                          \
    for (int i = t; i < (NITS)*16; i += 1024) b2l[i] = b2[(BASE_IT)*16 + i];   \
  } while(0)

#define CAB_STAGE(TGC, BASE) do {                                              \
    bf16x8 x_ = *(const bf16x8*)(cabGb + (size_t)(TGC)*1536 + lane*16);        \
    bf16x4 y_ = *(const bf16x4*)(cabGb + (size_t)(TGC)*1536 + 1024 + lane*8);  \
    *(bf16x8*)(myCab + (BASE) + lane*16) = x_;                                 \
    *(bf16x4*)(myCab + (BASE) + 1024 + lane*8) = y_;                           \
  } while(0)

// stage 16 cv rows (1536 B) of HALF for one tile: 24 B/lane (3 x bf16x4)
#define CV_STAGE_SUB(TGC, BASE, HALF, SUB) do {                                \
    const char* s_ = cvGb + (size_t)(TGC)*6144 + (HALF)*3072 + (SUB)*1536      \
                   + lane*24;                                                  \
    bf16x4 a_ = *(const bf16x4*)(s_);                                          \
    bf16x4 b_ = *(const bf16x4*)(s_ + 8);                                      \
    bf16x4 c_ = *(const bf16x4*)(s_ + 16);                                     \
    *(bf16x4*)(myCab + (BASE) + lane*24)      = a_;                            \
    *(bf16x4*)(myCab + (BASE) + lane*24 + 8)  = b_;                            \
    *(bf16x4*)(myCab + (BASE) + lane*24 + 16) = c_;                            \
  } while(0)

// One S pair-loop over the resident 48-it panel; partials in NAMED registers.
#define S_PAIR(SECOND, CBA, CBB, TA, TB) do {                                  \
    _Pragma("unroll 4")                                                        \
    for (int itl = 0; itl < 48; ++itl){                                        \
      bf16x8 B0_ = *(const bf16x8*)(panel + itl*2048 + laneOff);               \
      bf16x8 B1_ = *(const bf16x8*)(panel + itl*2048 + 1024 + laneOff);        \
      f32x4 dA_; dA_[0]=0;dA_[1]=0;dA_[2]=0;dA_[3]=0; f32x4 dB_ = dA_;         \
      dA_ = __builtin_amdgcn_mfma_f32_16x16x32_bf16(u##TA##_0, B0_, dA_, 0,0,0);\
      dB_ = __builtin_amdgcn_mfma_f32_16x16x32_bf16(u##TB##_0, B0_, dB_, 0,0,0);\
      dA_ = __builtin_amdgcn_mfma_f32_16x16x32_bf16(u##TA##_1, B1_, dA_, 0,0,0);\
      dB_ = __builtin_amdgcn_mfma_f32_16x16x32_bf16(u##TB##_1, B1_, dB_, 0,0,0);\
      const float bias_ = b2l[itl*16 + nlo];                                   \
      f32x2 bb_; bb_[0]=bias_; bb_[1]=bias_;                                   \
      f32x2 dAlo_ = __builtin_shufflevector(dA_,dA_,0,1) + bb_;                \
      f32x2 dAhi_ = __builtin_shufflevector(dA_,dA_,2,3) + bb_;                \
      f32x2 dBlo_ = __builtin_shufflevector(dB_,dB_,0,1) + bb_;                \
      f32x2 dBhi_ = __builtin_shufflevector(dB_,dB_,2,3) + bb_;                \
      const int r_ = (SECOND)*24 + (itl>>1);                                   \
      bf16x4 cA_ = *(const bf16x4*)(myCab + (CBA) + r_*32 + quad*8);           \
      bf16x4 cB_ = *(const bf16x4*)(myCab + (CBB) + r_*32 + quad*8);           \
      if (itl & 1){                                                            \
        s1l##TA += b4lo(cA_)*dAlo_; s1h##TA += b4hi(cA_)*dAhi_;                \
        s1l##TB += b4lo(cB_)*dBlo_; s1h##TB += b4hi(cB_)*dBhi_;                \
      } else {                                                                 \
        s0l##TA += b4lo(cA_)*dAlo_; s0h##TA += b4hi(cA_)*dAhi_;                \
        s0l##TB += b4lo(cB_)*dBlo_; s0h##TB += b4hi(cB_)*dBhi_;                \
      }                                                                        \
    }                                                                          \
  } while(0)

// One V pair-sub-loop: 16 panel its, coef sub-chunk resident at myCab 0/1536.
#define V_PAIR_SUB(SUB, TA, TB) do {                                           \
    _Pragma("unroll 4")                                                        \
    for (int il = 0; il < 16; ++il){                                           \
      const int gitl = (SUB)*16 + il;                                          \
      bf16x8 B0_ = *(const bf16x8*)(panel + gitl*2048 + laneOff);              \
      bf16x8 B1_ = *(const bf16x8*)(panel + gitl*2048 + 1024 + laneOff);       \
      f32x4 dA_; dA_[0]=0;dA_[1]=0;dA_[2]=0;dA_[3]=0; f32x4 dB_ = dA_;         \
      dA_ = __builtin_amdgcn_mfma_f32_16x16x32_bf16(u##TA##_0, B0_, dA_, 0,0,0);\
      dB_ = __builtin_amdgcn_mfma_f32_16x16x32_bf16(u##TB##_0, B0_, dB_, 0,0,0);\
      dA_ = __builtin_amdgcn_mfma_f32_16x16x32_bf16(u##TA##_1, B1_, dA_, 0,0,0);\
      dB_ = __builtin_amdgcn_mfma_f32_16x16x32_bf16(u##TB##_1, B1_, dB_, 0,0,0);\
      const float bias_ = b2l[gitl*16 + nlo];                                  \
      f32x2 bb_; bb_[0]=bias_; bb_[1]=bias_;                                   \
      f32x2 dAlo_ = __builtin_shufflevector(dA_,dA_,0,1) + bb_;                \
      f32x2 dAhi_ = __builtin_shufflevector(dA_,dA_,2,3) + bb_;                \
      f32x2 dBlo_ = __builtin_shufflevector(dB_,dB_,0,1) + bb_;                \
      f32x2 dBhi_ = __builtin_shufflevector(dB_,dB_,2,3) + bb_;                \
      const char* cbA_ = myCab + il*96;                                        \
      const char* cbB_ = myCab + 1536 + il*96;                                 \
      bf16x4 q0_ = *(const bf16x4*)(cbA_ + quad*8);                            \
      bf16x4 q1_ = *(const bf16x4*)(cbA_ + 32 + quad*8);                       \
      bf16x4 q2_ = *(const bf16x4*)(cbA_ + 64 + quad*8);                       \
      v0l##TA += b4lo(q0_)*dAlo_; v0h##TA += b4hi(q0_)*dAhi_;                  \
      v1l##TA += b4lo(q1_)*dAlo_; v1h##TA += b4hi(q1_)*dAhi_;                  \
      v2l##TA += b4lo(q2_)*dAlo_; v2h##TA += b4hi(q2_)*dAhi_;                  \
      q0_ = *(const bf16x4*)(cbB_ + quad*8);                                   \
      q1_ = *(const bf16x4*)(cbB_ + 32 + quad*8);                              \
      q2_ = *(const bf16x4*)(cbB_ + 64 + quad*8);                              \
      v0l##TB += b4lo(q0_)*dBlo_; v0h##TB += b4hi(q0_)*dBhi_;                  \
      v1l##TB += b4lo(q1_)*dBlo_; v1h##TB += b4hi(q1_)*dBhi_;                  \
      v2l##TB += b4lo(q2_)*dBlo_; v2h##TB += b4hi(q2_)*dBhi_;                  \
    }                                                                          \
  } while(0)

#define S_FLUSH(TG, S0LO, S0HI, S1LO, S1HI) do {                               \
      myOut[(eb+0)*56 + nlo] = S0LO[0];                                        \
      myOut[(eb+1)*56 + nlo] = S0LO[1];                                        \
      myOut[(eb+2)*56 + nlo] = S0HI[0];                                        \
      myOut[(eb+3)*56 + nlo] = S0HI[1];                                        \
      myOut[(eb+0)*56 + 16+nlo] = S1LO[0];                                     \
      myOut[(eb+1)*56 + 16+nlo] = S1LO[1];                                     \
      myOut[(eb+2)*56 + 16+nlo] = S1HI[0];                                     \
      myOut[(eb+3)*56 + 16+nlo] = S1HI[1];                                     \
      const int e0e = (TG)*16;                                                 \
      { int e = lane>>2, seg = lane&3, eg = e0e + e;                           \
        if (eg < E){                                                           \
          f32x4 m0 = *(const f32x4*)&myOut[e*56 + seg*8];                      \
          f32x4 m1 = *(const f32x4*)&myOut[e*56 + seg*8 + 4];                  \
          bf16x8 o; o[0]=(__bf16)m0[0]; o[1]=(__bf16)m0[1];                    \
          o[2]=(__bf16)m0[2]; o[3]=(__bf16)m0[3]; o[4]=(__bf16)m1[0];          \
          o[5]=(__bf16)m1[1]; o[6]=(__bf16)m1[2]; o[7]=(__bf16)m1[3];          \
          nt_store_b8(msgs + (size_t)permG[eg]*80 + seg*8, o);                 \
        } }                                                                    \
      for (int r8 = 0; r8 < 2; ++r8){                                          \
        int e = r8*8 + (lane>>3), kq = lane&7, eg = e0e + e;                   \
        f32x4 ms = *(const f32x4*)&myOut[e*56 + kq*4];                         \
        int dn = ei[(size_t)E + min(eg, E-1)];                                 \
        const float* kvp = kvt + (size_t)dn*32 + kq*4;                         \
        float part = ms[0]*kvp[0]+ms[1]*kvp[1]+ms[2]*kvp[2]+ms[3]*kvp[3];      \
        part += __shfl_xor(part, 1);                                           \
        part += __shfl_xor(part, 2);                                           \
        part += __shfl_xor(part, 4);                                           \
        if (kq == 0 && eg < E){                                                \
          float lg = (part + carr[dn]) * 0.35355339059327373f                  \
                   + logf(ntld_f(&env[eg]) + 1e-8f);                           \
          nt_store_f(&logits_s[permG[eg]], lg);                                \
        } }                                                                    \
  } while(0)

#define V_FLUSH(TG, V0LO, V0HI, V1LO, V1HI, V2LO, V2HI) do {                   \
      const int cb2 = nlo*3;                                                   \
      myOut[(eb+0)*56 + cb2+0] = V0LO[0];                                      \
      myOut[(eb+1)*56 + cb2+0] = V0LO[1];                                      \
      myOut[(eb+2)*56 + cb2+0] = V0HI[0];                                      \
      myOut[(eb+3)*56 + cb2+0] = V0HI[1];                                      \
      myOut[(eb+0)*56 + cb2+1] = V1LO[0];                                      \
      myOut[(eb+1)*56 + cb2+1] = V1LO[1];                                      \
      myOut[(eb+2)*56 + cb2+1] = V1HI[0];                                      \
      myOut[(eb+3)*56 + cb2+1] = V1HI[1];                                      \
      myOut[(eb+0)*56 + cb2+2] = V2LO[0];                                      \
      myOut[(eb+1)*56 + cb2+2] = V2LO[1];                                      \
      myOut[(eb+2)*56 + cb2+2] = V2HI[0];                                      \
      myOut[(eb+3)*56 + cb2+2] = V2HI[1];                                      \
      const int e0e = (TG)*16;                                                 \
      for (int i = lane; i < 96; i += 64){                                     \
        int e = i/6, seg = i - (i/6)*6, eg = e0e + e;                          \
        if (eg < E){                                                           \
          f32x4 m0 = *(const f32x4*)&myOut[e*56 + seg*8];                      \
          f32x4 m1 = *(const f32x4*)&myOut[e*56 + seg*8 + 4];                  \
          bf16x8 o; o[0]=(__bf16)m0[0]; o[1]=(__bf16)m0[1];                    \
          o[2]=(__bf16)m0[2]; o[3]=(__bf16)m0[3]; o[4]=(__bf16)m1[0];          \
          o[5]=(__bf16)m1[1]; o[6]=(__bf16)m1[2]; o[7]=(__bf16)m1[3];          \
          nt_store_b8(msgs + (size_t)permG[eg]*80 + 32 + seg*8, o);            \
        } }                                                                    \
  } while(0)

// Persistent-panel edge kernel: 256 blocks x 1024 threads (16 waves/CU =
// 4 waves/SIMD). Each wave owns 2 tiles (wgid, wgid+4096); partials in
// registers; cv staged in 16-it sub-chunks. R11-measured-best structure.
// LDS = 96K panel + 56K wstage + 3K b2l = 155 KB.
__global__ void __launch_bounds__(1024, 4) k_edge(
    const __bf16* __restrict__ W2t, const float* __restrict__ b2,
    const __bf16* __restrict__ uG, const __bf16* __restrict__ cabG,
    const __bf16* __restrict__ cvG, const int* __restrict__ ei,
    const int* __restrict__ permG, const float* __restrict__ kvt,
    const float* __restrict__ carr, const float* __restrict__ env,
    __bf16* __restrict__ msgs, float* __restrict__ logits_s, int E, int NT)
{
  __shared__ __align__(16) char panel[98304];      // 48 its x 2048 B (swizzled)
  __shared__ __align__(16) char wstage[16][3584];  // per wave: coef stage / out alias
  __shared__ float b2l[768];

  const int t = threadIdx.x;
  const int lane = t & 63;
  const int wv   = t >> 6;
  const int quad = lane >> 4;
  const int nlo  = lane & 15;
  const int wgid = blockIdx.x*16 + wv;
  const int laneOff = quad*256 + nlo*16;
  const int uOff    = quad*256 + nlo*16;
  char*  myCab = wstage[wv];
  float* myOut = (float*)wstage[wv];      // aliases coef stage (flush after loops only)
  const char* w2b   = (const char*)W2t;
  const char* uGb   = (const char*)uG;
  const char* cabGb = (const char*)cabG;
  const char* cvGb  = (const char*)cvG;

  const int tA = wgid, tB = wgid + 4096;
  const bool hA = tA < NT, hB = tB < NT;
  const int cA = min(tA, NT-1), cB = min(tB, NT-1);

  // ---- hoisted u fragments (used in all 4 phases)
  const bf16x8 uA_0 = *(const bf16x8*)(uGb + (size_t)cA*2048 + uOff);
  const bf16x8 uA_1 = *(const bf16x8*)(uGb + (size_t)cA*2048 + 1024 + uOff);
  const bf16x8 uB_0 = *(const bf16x8*)(uGb + (size_t)cB*2048 + uOff);
  const bf16x8 uB_1 = *(const bf16x8*)(uGb + (size_t)cB*2048 + 1024 + uOff);

  // ---- S partials (registers, live S0->S1)
  f32x2 s0lA={0,0}, s0hA={0,0}, s1lA={0,0}, s1hA={0,0};
  f32x2 s0lB={0,0}, s0hB={0,0}, s1lB={0,0}, s1hB={0,0};

  const int eb = quad*4;

  // ---- S phases: cab staged ONCE (2 tiles = 3072 B), reused in S1
  LOAD_PANEL(0, 48);
  CAB_STAGE(cA, 0); CAB_STAGE(cB, 1536);
  __syncthreads();
  S_PAIR(0, 0, 1536, A, B);
  __syncthreads();
  LOAD_PANEL(48, 48);
  __syncthreads();
  S_PAIR(1, 0, 1536, A, B);
  if (hA) S_FLUSH(tA, s0lA, s0hA, s1lA, s1hA);
  if (hB) S_FLUSH(tB, s0lB, s0hB, s1lB, s1hB);
  __syncthreads();

  // ---- V partials (registers, live V0->V1)
  f32x2 v0lA={0,0}, v0hA={0,0}, v1lA={0,0}, v1hA={0,0}, v2lA={0,0}, v2hA={0,0};
  f32x2 v0lB={0,0}, v0hB={0,0}, v1lB={0,0}, v1hB={0,0}, v2lB={0,0}, v2hB={0,0};

  LOAD_PANEL(96, 32);
  __syncthreads();
  CV_STAGE_SUB(cA, 0, 0, 0); CV_STAGE_SUB(cB, 1536, 0, 0);
  V_PAIR_SUB(0, A, B);
  CV_STAGE_SUB(cA, 0, 0, 1); CV_STAGE_SUB(cB, 1536, 0, 1);
  V_PAIR_SUB(1, A, B);
  __syncthreads();
  LOAD_PANEL(128, 32);
  __syncthreads();
  CV_STAGE_SUB(cA, 0, 1, 0); CV_STAGE_SUB(cB, 1536, 1, 0);
  V_PAIR_SUB(0, A, B);
  CV_STAGE_SUB(cA, 0, 1, 1); CV_STAGE_SUB(cB, 1536, 1, 1);
  V_PAIR_SUB(1, A, B);
  if (hA) V_FLUSH(tA, v0lA, v0hA, v1lA, v1hA, v2lA, v2hA);
  if (hB) V_FLUSH(tB, v0lB, v0hB, v1lB, v1hB, v2lB, v2hB);
}

// One wave per node: max pass, merged gather+den pass (bf16 msgs, NT loads),
// fused node matmuls + gate + residual + BN stats.
__global__ void __launch_bounds__(256) k_agg(
    const __bf16* __restrict__ msgs, const float* __restrict__ logits_s,
    const int* __restrict__ cursor, const float* __restrict__ nf,
    const float* __restrict__ Wout_s, const float* __restrict__ Wout_v,
    const float* __restrict__ Wg_s, const float* __restrict__ Wg_v,
    float* __restrict__ xbuf, float* __restrict__ bnacc, int N)
{
  __shared__ float aggl[4][80];
  __shared__ float t1[4][96];
  __shared__ float t2[4][96];
  __shared__ float bnl[80];
  const int t = threadIdx.x, l = t & 63, wv = t >> 6;
  const int n = blockIdx.x*4 + wv;
  const bool act = (n < N);
  const int nc = act ? n : (N-1);
  if (t < 80) bnl[t] = 0.f;

  const int r0 = (nc == 0) ? 0 : cursor[nc-1];
  const int r1 = cursor[nc];
  const int deg = act ? (r1 - r0) : 0;

  float mym = -3.4e38f;
  for (int i = l; i < deg; i += 64) mym = fmaxf(mym, logits_s[r0+i]);
  #pragma unroll
  for (int s = 32; s; s >>= 1) mym = fmaxf(mym, __shfl_xor(mym, s));
  float denp = 0.f, acc0 = 0.f, acc1 = 0.f;
  for (int c0 = 0; c0 < deg; c0 += 64){
    const int len = min(64, deg - c0);
    float ex = 0.f;
    if (l < len) ex = __expf(logits_s[r0+c0+l] - mym);
    denp += ex;
    for (int j0 = 0; j0 < len; j0 += 4){
      const int jn = len - j0;
      const __bf16* base = msgs + (size_t)(r0+c0+j0)*80;
      float v0=0,v1=0,v2=0,v3=0, w0=0,w1=0,w2=0,w3=0;
      float a0_=0,a1_=0,a2_=0,a3_=0;
      v0 = ntbf(&base[l]); if (l < 16) w0 = ntbf(&base[64+l]); a0_ = __shfl(ex, j0);
      if (jn > 1){ v1 = ntbf(&base[80+l]);  if (l < 16) w1 = ntbf(&base[144+l]); a1_ = __shfl(ex, j0+1); }
      if (jn > 2){ v2 = ntbf(&base[160+l]); if (l < 16) w2 = ntbf(&base[224+l]); a2_ = __shfl(ex, j0+2); }
      if (jn > 3){ v3 = ntbf(&base[240+l]); if (l < 16) w3 = ntbf(&base[304+l]); a3_ = __shfl(ex, j0+3); }
      acc0 += a0_*v0 + a1_*v1 + a2_*v2 + a3_*v3;
      if (l < 16) acc1 += a0_*w0 + a1_*w1 + a2_*w2 + a3_*w3;
    }
  }
  #pragma unroll
  for (int s = 32; s; s >>= 1) denp += __shfl_xor(denp, s);
  const float inv = 1.f/(denp + 1e-8f);
  aggl[wv][l] = acc0 * inv;
  if (l < 16) aggl[wv][64+l] = acc1 * inv;
  __syncthreads();

  const float* arow = &aggl[wv][0];
  const float iS = 0.17677669529663687f;  // 1/sqrt(32)
  const float iV = 0.25f;                 // 1/sqrt(16)
  for (int o = l; o < 80; o += 64){
    float val = 0.f;
    if (o < 32){
      for (int s = 0; s < 32; ++s) val += arow[s]*Wout_s[s*32+o];
      val *= iS;
    } else {
      int w = (o-32)/3, c = (o-32)-w*3;
      for (int v = 0; v < 16; ++v) val += arow[32+v*3+c]*Wout_v[v*16+w];
      val *= iV;
    }
    t1[wv][o] = val;
  }
  __syncthreads();
  for (int o = l; o < 96; o += 64){
    float val = 0.f;
    if (o < 48){
      for (int k = 0; k < 32; ++k) val += t1[wv][k]*Wg_s[k*48+o];
      val *= iS;
    } else {
      int w = (o-48)/3, c = (o-48)-w*3;
      for (int v = 0; v < 16; ++v) val += t1[wv][32+v*3+c]*Wg_v[v*16+w];
      val *= iV;
    }
    t2[wv][o] = val;
  }
  __syncthreads();
  for (int o = l; o < 80; o += 64){
    float x;
    if (o < 32){
      x = silu_f(t2[wv][o]) + nf[(size_t)nc*80+o];
      if (act){
        nt_store_f(&xbuf[(size_t)n*80+o], x);
        atomicAdd(&bnl[o], x);
        atomicAdd(&bnl[32+o], x*x);
      }
    } else {
      int w = (o-32)/3;
      x = sigm_f(t2[wv][32+w]) * t2[wv][48+(o-32)] + nf[(size_t)nc*80+o];
      if (act){
        nt_store_f(&xbuf[(size_t)n*80+o], x);
        atomicAdd(&bnl[64+w], x*x);
      }
    }
  }
  __syncthreads();
  if (t < 80) atomicAdd(&bnacc[t], bnl[t]);
}

__global__ void __launch_bounds__(256) k_out(const float* __restrict__ xbuf,
    const float* __restrict__ bnacc,
    const float* __restrict__ bn_ws, const float* __restrict__ bn_bs,
    const float* __restrict__ bn_wv, float* __restrict__ out, int N){
  __shared__ float coef[80];
  int t = threadIdx.x;
  float fN = (float)N;
  if (t < 32){
    float mean = bnacc[t]/fN;
    float var = bnacc[32+t]/fN - mean*mean;
    float cm = bn_ws[t]*rsqrtf(var + 1e-5f);
    coef[t] = cm;
    coef[32+t] = bn_bs[t] - mean*cm;
  } else if (t < 48){
    int v = t - 32;
    coef[64+v] = bn_wv[v]*rsqrtf(bnacc[64+v]/(3.f*fN) + 1e-5f);
  }
  __syncthreads();
  int i = blockIdx.x*256 + t;
  if (i >= N*80) return;
  int o = i - (i/80)*80;
  float x = ntld_f(&xbuf[i]);
  nt_store_f(&out[i], (o < 32) ? (x*coef[o] + coef[32+o]) : (x*coef[64+(o-32)/3]));
}

extern "C" void kernel_launch(void* const* d_in, const int* in_sizes, int n_in,
                              void* d_out, int out_size, void* d_ws, size_t ws_size,
                              hipStream_t stream) {
  const float* nf     = (const float*)d_in[0];
  const int*   ei     = (const int*)  d_in[1];
  const float* sh     = (const float*)d_in[2];
  const float* radial = (const float*)d_in[3];
  const float* env    = (const float*)d_in[4];
  const float* W1     = (const float*)d_in[5];
  const float* b1     = (const float*)d_in[6];
  const float* W2     = (const float*)d_in[7];
  const float* b2     = (const float*)d_in[8];
  const float* Wq     = (const float*)d_in[9];
  const float* bq     = (const float*)d_in[10];
  const float* Wk     = (const float*)d_in[11];
  const float* bk     = (const float*)d_in[12];
  const float* Wout_s = (const float*)d_in[13];
  const float* Wout_v = (const float*)d_in[14];
  const float* Wg_s   = (const float*)d_in[15];
  const float* Wg_v   = (const float*)d_in[16];
  const float* bn_ws  = (const float*)d_in[17];
  const float* bn_bs  = (const float*)d_in[18];
  const float* bn_wv  = (const float*)d_in[19];

  const int E = in_sizes[4];
  const int N = in_sizes[0] / 80;
  const int NT = (E + 15)/16;

  float* ws = (float*)d_ws;
  size_t off = 0;
  __bf16* w2t    = (__bf16*)(ws + off); off += 81920;          // 320 KB bf16
  __bf16* msgs   = (__bf16*)(ws + off); off += (size_t)E*40;   // E*80 bf16
  float* logits_s= ws + off; off += E;
  int* cnt       = (int*)(ws + off); off += N;
  int* cursor    = (int*)(ws + off); off += N;
  float* xbuf    = ws + off; off += (size_t)N*80;
  float* bnacc   = ws + off; off += 80;
  float* kvt     = ws + off; off += (size_t)N*32;
  float* carr    = ws + off; off += N;
  int* permG     = (int*)(ws + off); off += E;
  __bf16* uG     = (__bf16*)(ws + off); off += (size_t)NT*512;   // NT*2048 B
  __bf16* cabG   = (__bf16*)(ws + off); off += (size_t)NT*384;   // NT*1536 B
  __bf16* cvG    = (__bf16*)(ws + off); off += (size_t)NT*1536;  // NT*6144 B

  hipMemsetAsync(cnt, 0, (size_t)N*sizeof(int), stream);

  const int nbPrep = 640;                 // 163840/256
  const int nbHist = (E + 255)/256;
  const int nbKv   = (N + 63)/64;
  k_setup<<<nbPrep + nbHist + nbKv, 256, 0, stream>>>(W2, w2t, ei, cnt,
      nf, Wq, bq, Wk, bk, kvt, carr, nbPrep, nbHist, N, E);
  k_scan<<<1, 1024, 0, stream>>>(cnt, cursor, bnacc, N, E);
  k_prep<<<(E + 63)/64, 256, 0, stream>>>(nf, ei, sh, radial, W1, b1, cursor,
      uG, cabG, cvG, permG, E, NT);
  k_edge<<<256, 1024, 0, stream>>>(w2t, b2, uG, cabG, cvG, ei, permG,
      kvt, carr, env, msgs, logits_s, E, NT);
  k_agg<<<(N + 3)/4, 256, 0, stream>>>(msgs, logits_s, cursor, nf,
      Wout_s, Wout_v, Wg_s, Wg_v, xbuf, bnacc, N);
  k_out<<<(N*80 + 255)/256, 256, 0, stream>>>(xbuf, bnacc, bn_ws, bn_bs, bn_wv,
      (float*)d_out, N);
}